// Round 9
// baseline (133.778 us; speedup 1.0000x reference)
//
#include <hip/hip_runtime.h>

typedef _Float16 h16;
typedef _Float16 h16x4 __attribute__((ext_vector_type(4)));
typedef _Float16 h16x8 __attribute__((ext_vector_type(8)));
typedef __fp16 fp16x2 __attribute__((ext_vector_type(2)));   // cvt_pkrtz native type
typedef float f32x4 __attribute__((ext_vector_type(4)));

#define SEQ 2048
#define RSTRIDE 8192   // b*h*d = 4*16*128
#define QTILE 256
#define NQT (SEQ / QTILE)   // 8
#define KBLK 64
#define KPAD 136       // K LDS row stride (halves)
#define VPAD 72        // Vt LDS row stride (halves)
#define DEFER_THR 8.0f

static __device__ __forceinline__ h16x8 pack8(f32x4 a, f32x4 b) {
    union { fp16x2 h2[4]; h16x8 h8; } u;
    u.h2[0] = __builtin_amdgcn_cvt_pkrtz(a[0], a[1]);
    u.h2[1] = __builtin_amdgcn_cvt_pkrtz(a[2], a[3]);
    u.h2[2] = __builtin_amdgcn_cvt_pkrtz(b[0], b[1]);
    u.h2[3] = __builtin_amdgcn_cvt_pkrtz(b[2], b[3]);
    return u.h8;
}

static __device__ __forceinline__ h16x4 pack4(float x0, float x1, float x2, float x3) {
    union { fp16x2 h2[2]; h16x4 h4; } u;
    u.h2[0] = __builtin_amdgcn_cvt_pkrtz(x0, x1);
    u.h2[1] = __builtin_amdgcn_cvt_pkrtz(x2, x3);
    return u.h4;
}

__global__ __launch_bounds__(512, 2)
void fa_fwd_kernel(const float* __restrict__ Qg, const float* __restrict__ Kg,
                   const float* __restrict__ Vg, float* __restrict__ Out)
{
    __shared__ __attribute__((aligned(16))) h16 Kl[2][KBLK * KPAD];   // [key][d]
    __shared__ __attribute__((aligned(16))) h16 Vt[2][128 * VPAD];    // [d][key^swz]

    // 512 blocks, 2/CU: blocks b and b+256 share a CU and form the balanced
    // causal pair (qt = bx and 7-bx) for the SAME bh. XCD x owns bh {8x..8x+7}.
    const int b   = (int)blockIdx.x;   // 0..511
    const int idx = b & 255;
    const int bx  = (idx >> 3) & 3;               // 0..3
    const int bh  = 8 * (idx & 7) + (idx >> 5);   // 0..63
    const int qt  = (b >> 8) ? (NQT - 1 - bx) : bx;
    const int tid  = threadIdx.x;   // 0..511 (8 waves)
    const int wave = tid >> 6;
    const int lane = tid & 63;
    const int lg   = lane >> 4;
    const int lc   = lane & 15;
    const size_t bhoff = (size_t)bh * 128;
    const float NEGINF = -__builtin_inff();
    const float SL = 0.08838834764831845f * 1.4426950408889634f;  // (1/sqrt(128))*log2(e)

    // ---- K staging geometry
    const int krow = tid >> 4;            // 0..31 (+32*it)
    const int kd0  = (tid & 15) * 8;
    const float* kbase = Kg + (size_t)krow * RSTRIDE + bhoff + kd0;
    const int kwoff = krow * KPAD + kd0;

    // ---- V staging geometry
    const int vkey0 = 4 * (tid >> 5);     // 0..60
    const int vd0   = 4 * (tid & 31);     // 0..124
    const int vcol  = vkey0 ^ (4 * (tid & 15));
    const float* vbase = Vg + (size_t)vkey0 * RSTRIDE + bhoff + vd0;

    // ---- per-lane LDS fragment bases
    const int kfoff = lc * KPAD + lg * 8;                      // + kt*16*KPAD + dk*32
    const int vfoff = lc * VPAD + ((4 * lg) ^ (4 * (lc >> 2)));// + dt*16*VPAD + 16*((2u+s)^(dt&3))

    f32x4 kra[2], krb[2], vra[4];   // prefetch registers (T14)

    const int q0 = qt * QTILE;
    const int wbase = q0 + wave * 32;    // wave's 32 q-rows (2 fused strips)

    // ---- Q fragments, pre-scaled
    h16x8 qf[2][4];
#pragma unroll
    for (int s2 = 0; s2 < 2; ++s2) {
        const int qrow = wbase + s2 * 16 + lc;
        const float* qp = Qg + (size_t)qrow * RSTRIDE + bhoff + lg * 8;
#pragma unroll
        for (int dk = 0; dk < 4; ++dk) {
            f32x4 a = *(const f32x4*)(qp + dk * 32);
            f32x4 b2 = *(const f32x4*)(qp + dk * 32 + 4);
#pragma unroll
            for (int j = 0; j < 4; ++j) { a[j] *= SL; b2[j] *= SL; }
            qf[s2][dk] = pack8(a, b2);
        }
    }

    f32x4 o[2][8];
#pragma unroll
    for (int s2 = 0; s2 < 2; ++s2)
#pragma unroll
        for (int dt = 0; dt < 8; ++dt) o[s2][dt] = f32x4{0.f, 0.f, 0.f, 0.f};
    float mreg[2] = {NEGINF, NEGINF};
    float lsum[2] = {0.f, 0.f};

    const int nkv = 4 * (qt + 1);

    // ---- prologue: load t0 -> regs, write buf0, load t1 -> regs, barrier
#pragma unroll
    for (int it = 0; it < 2; ++it) {
        const float* gp = kbase + (size_t)(32 * it) * RSTRIDE;
        kra[it] = *(const f32x4*)gp;
        krb[it] = *(const f32x4*)(gp + 4);
    }
#pragma unroll
    for (int kk = 0; kk < 4; ++kk)
        vra[kk] = *(const f32x4*)(vbase + (size_t)kk * RSTRIDE);
    {
        h16* kw = &Kl[0][kwoff];
#pragma unroll
        for (int it = 0; it < 2; ++it)
            *(h16x8*)(kw + it * 32 * KPAD) = pack8(kra[it], krb[it]);
#pragma unroll
        for (int e = 0; e < 4; ++e)
            *(h16x4*)&Vt[0][(vd0 + e) * VPAD + vcol] =
                pack4(vra[0][e], vra[1][e], vra[2][e], vra[3][e]);
    }
    if (nkv > 1) {
        const size_t toff = (size_t)KBLK * RSTRIDE;
#pragma unroll
        for (int it = 0; it < 2; ++it) {
            const float* gp = kbase + toff + (size_t)(32 * it) * RSTRIDE;
            kra[it] = *(const f32x4*)gp;
            krb[it] = *(const f32x4*)(gp + 4);
        }
#pragma unroll
        for (int kk = 0; kk < 4; ++kk)
            vra[kk] = *(const f32x4*)(vbase + toff + (size_t)kk * RSTRIDE);
    }
    __syncthreads();   // buf0 visible

    for (int t = 0; t < nkv; ++t) {
        const int kv0 = t * KBLK;
        const int cb = t & 1;

        // ---- write staged regs (tile t+1) -> other buffer (overlaps compute)
        if (t + 1 < nkv) {
            h16* kw = &Kl[cb ^ 1][kwoff];
#pragma unroll
            for (int it = 0; it < 2; ++it)
                *(h16x8*)(kw + it * 32 * KPAD) = pack8(kra[it], krb[it]);
#pragma unroll
            for (int e = 0; e < 4; ++e)
                *(h16x4*)&Vt[cb ^ 1][(vd0 + e) * VPAD + vcol] =
                    pack4(vra[0][e], vra[1][e], vra[2][e], vra[3][e]);
        }
        // ---- issue tile t+2 global loads
        if (t + 2 < nkv) {
            const size_t toff = (size_t)(kv0 + 2 * KBLK) * RSTRIDE;
#pragma unroll
            for (int it = 0; it < 2; ++it) {
                const float* gp = kbase + toff + (size_t)(32 * it) * RSTRIDE;
                kra[it] = *(const f32x4*)gp;
                krb[it] = *(const f32x4*)(gp + 4);
            }
#pragma unroll
            for (int kk = 0; kk < 4; ++kk)
                vra[kk] = *(const f32x4*)(vbase + toff + (size_t)kk * RSTRIDE);
        }

        // ---- fused compute: both strips share every LDS fragment load
        if (kv0 <= wbase + 31) {           // wave-uniform
            const h16* Kfb = &Kl[cb][kfoff];
            const h16* Vfb = &Vt[cb][vfoff];

            // S^T = K . Q^T for both strips: 1 load -> 2 MFMAs
            f32x4 sacc[2][4];
#pragma unroll
            for (int s2 = 0; s2 < 2; ++s2)
#pragma unroll
                for (int kt = 0; kt < 4; ++kt) sacc[s2][kt] = f32x4{0.f, 0.f, 0.f, 0.f};
            __builtin_amdgcn_s_setprio(1);
#pragma unroll
            for (int kt = 0; kt < 4; ++kt) {
#pragma unroll
                for (int dk = 0; dk < 4; ++dk) {
                    h16x8 a = *(const h16x8*)(Kfb + kt * 16 * KPAD + dk * 32);
                    sacc[0][kt] = __builtin_amdgcn_mfma_f32_16x16x32_f16(a, qf[0][dk], sacc[0][kt], 0, 0, 0);
                    sacc[1][kt] = __builtin_amdgcn_mfma_f32_16x16x32_f16(a, qf[1][dk], sacc[1][kt], 0, 0, 0);
                }
            }
            __builtin_amdgcn_s_setprio(0);

            // masks + per-lane max
            float vmax[2] = {NEGINF, NEGINF};
            if (kv0 + 63 <= wbase) {       // interior for both strips
#pragma unroll
                for (int s2 = 0; s2 < 2; ++s2)
#pragma unroll
                    for (int kt = 0; kt < 4; ++kt)
#pragma unroll
                        for (int r = 0; r < 4; ++r) vmax[s2] = fmaxf(vmax[s2], sacc[s2][kt][r]);
            } else {
#pragma unroll
                for (int s2 = 0; s2 < 2; ++s2) {
                    const int qrow = wbase + s2 * 16 + lc;
#pragma unroll
                    for (int kt = 0; kt < 4; ++kt)
#pragma unroll
                        for (int r = 0; r < 4; ++r) {
                            const int key = kv0 + 16 * kt + 4 * lg + r;
                            float sv = (key <= qrow) ? sacc[s2][kt][r] : NEGINF;
                            sacc[s2][kt][r] = sv;
                            vmax[s2] = fmaxf(vmax[s2], sv);
                        }
                }
            }

            // per-strip online softmax (T13 defer-max) + P fragments
            h16x8 pa[2][2];
#pragma unroll
            for (int s2 = 0; s2 < 2; ++s2) {
                if (__any(vmax[s2] > mreg[s2] + DEFER_THR)) {
                    float rmax = fmaxf(vmax[s2], __shfl_xor(vmax[s2], 16, 64));
                    rmax = fmaxf(rmax, __shfl_xor(rmax, 32, 64));
                    const float mnew  = fmaxf(mreg[s2], rmax);
                    const float alpha = __builtin_amdgcn_exp2f(mreg[s2] - mnew);
                    mreg[s2] = mnew;
                    lsum[s2] *= alpha;
#pragma unroll
                    for (int r = 0; r < 4; ++r) {
                        const float ar = __shfl(alpha, 4 * lg + r, 64);
#pragma unroll
                        for (int dt = 0; dt < 8; ++dt) o[s2][dt][r] *= ar;
                    }
                }
                float psum = 0.f;
#pragma unroll
                for (int kt = 0; kt < 4; ++kt)
#pragma unroll
                    for (int r = 0; r < 4; ++r) {
                        const float e = __builtin_amdgcn_exp2f(sacc[s2][kt][r] - mreg[s2]);
                        sacc[s2][kt][r] = e;
                        psum += e;
                    }
                lsum[s2] += psum;
#pragma unroll
                for (int u = 0; u < 2; ++u)
                    pa[s2][u] = pack8(sacc[s2][2 * u], sacc[s2][2 * u + 1]);
            }

            // PV for both strips: 1 fragment load -> 2 MFMAs
            __builtin_amdgcn_s_setprio(1);
#pragma unroll
            for (int dt = 0; dt < 8; ++dt) {
#pragma unroll
                for (int u = 0; u < 2; ++u) {
                    union { h16x8 v8; h16x4 v4[2]; } bv;
                    bv.v4[0] = *(const h16x4*)(Vfb + dt * 16 * VPAD + 16 * ((2 * u + 0) ^ (dt & 3)));
                    bv.v4[1] = *(const h16x4*)(Vfb + dt * 16 * VPAD + 16 * ((2 * u + 1) ^ (dt & 3)));
                    o[0][dt] = __builtin_amdgcn_mfma_f32_16x16x32_f16(pa[0][u], bv.v8, o[0][dt], 0, 0, 0);
                    o[1][dt] = __builtin_amdgcn_mfma_f32_16x16x32_f16(pa[1][u], bv.v8, o[1][dt], 0, 0, 0);
                }
            }
            __builtin_amdgcn_s_setprio(0);
        }
        __syncthreads();   // single barrier per tile
    } // kv tiles

    // ---- epilogue
#pragma unroll
    for (int s2 = 0; s2 < 2; ++s2) {
        float ls = lsum[s2];
        ls += __shfl_xor(ls, 16, 64);
        ls += __shfl_xor(ls, 32, 64);
#pragma unroll
        for (int r = 0; r < 4; ++r) {
            const float lr  = __shfl(ls, 4 * lg + r, 64);
            const float inv = 1.0f / lr;
            const int qrow  = wbase + s2 * 16 + 4 * lg + r;
            float* op = Out + (size_t)qrow * RSTRIDE + bhoff + lc;
#pragma unroll
            for (int dt = 0; dt < 8; ++dt) op[dt * 16] = o[s2][dt][r] * inv;
        }
    }
}

extern "C" void kernel_launch(void* const* d_in, const int* in_sizes, int n_in,
                              void* d_out, int out_size, void* d_ws, size_t ws_size,
                              hipStream_t stream) {
    (void)in_sizes; (void)n_in; (void)out_size; (void)d_ws; (void)ws_size;
    const float* Q = (const float*)d_in[0];
    const float* K = (const float*)d_in[1];
    const float* V = (const float*)d_in[2];
    float* O = (float*)d_out;
    fa_fwd_kernel<<<dim3(512), 512, 0, stream>>>(Q, K, V, O);
}

// Round 10
// 125.419 us; speedup vs baseline: 1.0667x; 1.0667x over previous
//
#include <hip/hip_runtime.h>

typedef _Float16 h16;
typedef _Float16 h16x4 __attribute__((ext_vector_type(4)));
typedef _Float16 h16x8 __attribute__((ext_vector_type(8)));
typedef __fp16 fp16x2 __attribute__((ext_vector_type(2)));   // cvt_pkrtz native type
typedef float f32x4 __attribute__((ext_vector_type(4)));

#define SEQ 2048
#define RSTRIDE 8192   // b*h*d = 4*16*128
#define QTILE 256
#define NQT (SEQ / QTILE)   // 8
#define KBLK 64
#define KPAD 136       // K LDS row stride (halves)
#define VPAD 72        // Vt LDS row stride (halves)
#define DEFER_THR 8.0f

static __device__ __forceinline__ h16x8 pack8(f32x4 a, f32x4 b) {
    union { fp16x2 h2[4]; h16x8 h8; } u;
    u.h2[0] = __builtin_amdgcn_cvt_pkrtz(a[0], a[1]);
    u.h2[1] = __builtin_amdgcn_cvt_pkrtz(a[2], a[3]);
    u.h2[2] = __builtin_amdgcn_cvt_pkrtz(b[0], b[1]);
    u.h2[3] = __builtin_amdgcn_cvt_pkrtz(b[2], b[3]);
    return u.h8;
}

static __device__ __forceinline__ h16x4 pack4(float x0, float x1, float x2, float x3) {
    union { fp16x2 h2[2]; h16x4 h4; } u;
    u.h2[0] = __builtin_amdgcn_cvt_pkrtz(x0, x1);
    u.h2[1] = __builtin_amdgcn_cvt_pkrtz(x2, x3);
    return u.h4;
}

__global__ __launch_bounds__(512, 2)
void fa_fwd_kernel(const float* __restrict__ Qg, const float* __restrict__ Kg,
                   const float* __restrict__ Vg, float* __restrict__ Out)
{
    __shared__ __attribute__((aligned(16))) h16 Kl[2][KBLK * KPAD];   // [key][d]
    __shared__ __attribute__((aligned(16))) h16 Vt[3][128 * VPAD];    // [d][key^swz], triple buf

    // R8 mapping: grid (4,64); XCD x owns bh {8x..8x+7}; pairs (bx, 7-bx) in-block
    const int lin = (int)blockIdx.x + 4 * (int)blockIdx.y;
    const int bx  = (lin >> 3) & 3;               // 0..3
    const int bh  = 8 * (lin & 7) + (lin >> 5);   // 0..63
    const int tid  = threadIdx.x;   // 0..511 (8 waves)
    const int wave = tid >> 6;
    const int lane = tid & 63;
    const int lg   = lane >> 4;
    const int lc   = lane & 15;
    const size_t bhoff = (size_t)bh * 128;
    const float NEGINF = -__builtin_inff();
    const float SL = 0.08838834764831845f * 1.4426950408889634f;  // (1/sqrt(128))*log2(e)

    // ---- K staging geometry
    const int krow = tid >> 4;            // 0..31 (+32*it)
    const int kd0  = (tid & 15) * 8;
    const float* kbase = Kg + (size_t)krow * RSTRIDE + bhoff + kd0;
    const int kwoff = krow * KPAD + kd0;

    // ---- V staging geometry
    const int vkey0 = 4 * (tid >> 5);     // 0..60
    const int vd0   = 4 * (tid & 31);     // 0..124
    const int vcol  = vkey0 ^ (4 * (tid & 15));
    const float* vbase = Vg + (size_t)vkey0 * RSTRIDE + bhoff + vd0;

    // ---- per-lane LDS fragment bases
    const int kfoff = lc * KPAD + lg * 8;                      // + kt*16*KPAD + dk*32
    const int vfoff = lc * VPAD + ((4 * lg) ^ (4 * (lc >> 2)));// + dt*16*VPAD + 16*((2u+s)^(dt&3))

    f32x4 kra[2], krb[2], vra[4];   // prefetch registers (T14)

    for (int half = 0; half < 2; ++half) {
        const int qt = half ? (NQT - 1 - bx) : bx;
        const int q0 = qt * QTILE;
        const int wbase = q0 + wave * 32;    // wave's 32 q-rows (2 fused strips)

        // ---- Q fragments, pre-scaled
        h16x8 qf[2][4];
#pragma unroll
        for (int s2 = 0; s2 < 2; ++s2) {
            const int qrow = wbase + s2 * 16 + lc;
            const float* qp = Qg + (size_t)qrow * RSTRIDE + bhoff + lg * 8;
#pragma unroll
            for (int dk = 0; dk < 4; ++dk) {
                f32x4 a = *(const f32x4*)(qp + dk * 32);
                f32x4 b2 = *(const f32x4*)(qp + dk * 32 + 4);
#pragma unroll
                for (int j = 0; j < 4; ++j) { a[j] *= SL; b2[j] *= SL; }
                qf[s2][dk] = pack8(a, b2);
            }
        }

        f32x4 o[2][8];
#pragma unroll
        for (int s2 = 0; s2 < 2; ++s2)
#pragma unroll
            for (int dt = 0; dt < 8; ++dt) o[s2][dt] = f32x4{0.f, 0.f, 0.f, 0.f};
        float mreg[2] = {NEGINF, NEGINF};
        float lsum[2] = {0.f, 0.f};

        h16x8 paA[2][2], paB[2][2];      // static double-buffered P fragments (T15)
#pragma unroll
        for (int s2 = 0; s2 < 2; ++s2)
#pragma unroll
            for (int u = 0; u < 2; ++u) paA[s2][u] = h16x8{0,0,0,0,0,0,0,0};

        const int nkv = 4 * (qt + 1);    // always even

        h16* vprev_ = Vt[2];   // buf of tile t-1 (garbage at t=0; do_pv=false)
        h16* vcurr_ = Vt[0];   // buf of tile t
        h16* vnext_ = Vt[1];   // buf of tile t+1 (write target)

        // ---- prologue: load t0 -> regs
#pragma unroll
        for (int it = 0; it < 2; ++it) {
            const float* gp = kbase + (size_t)(32 * it) * RSTRIDE;
            kra[it] = *(const f32x4*)gp;
            krb[it] = *(const f32x4*)(gp + 4);
        }
#pragma unroll
        for (int kk = 0; kk < 4; ++kk)
            vra[kk] = *(const f32x4*)(vbase + (size_t)kk * RSTRIDE);
        __syncthreads();   // previous half's compute (incl. drain PV) done before overwrite
        {
            h16* kw = &Kl[0][kwoff];
#pragma unroll
            for (int it = 0; it < 2; ++it)
                *(h16x8*)(kw + it * 32 * KPAD) = pack8(kra[it], krb[it]);
#pragma unroll
            for (int e = 0; e < 4; ++e)
                *(h16x4*)&vcurr_[(vd0 + e) * VPAD + vcol] =
                    pack4(vra[0][e], vra[1][e], vra[2][e], vra[3][e]);
        }
        if (nkv > 1) {
            const size_t toff = (size_t)KBLK * RSTRIDE;
#pragma unroll
            for (int it = 0; it < 2; ++it) {
                const float* gp = kbase + toff + (size_t)(32 * it) * RSTRIDE;
                kra[it] = *(const f32x4*)gp;
                krb[it] = *(const f32x4*)(gp + 4);
            }
#pragma unroll
            for (int kk = 0; kk < 4; ++kk)
                vra[kk] = *(const f32x4*)(vbase + toff + (size_t)kk * RSTRIDE);
        }
        __syncthreads();   // buf0 visible

        // ---- PV helper: 1 V-fragment load -> 2 MFMAs (both strips)
        auto pv_fn = [&](const h16* Vfb, h16x8 (&pap)[2][2]) {
            __builtin_amdgcn_s_setprio(1);
#pragma unroll
            for (int dt = 0; dt < 8; ++dt) {
#pragma unroll
                for (int u = 0; u < 2; ++u) {
                    union { h16x8 v8; h16x4 v4[2]; } bv;
                    bv.v4[0] = *(const h16x4*)(Vfb + dt * 16 * VPAD + 16 * ((2 * u + 0) ^ (dt & 3)));
                    bv.v4[1] = *(const h16x4*)(Vfb + dt * 16 * VPAD + 16 * ((2 * u + 1) ^ (dt & 3)));
                    o[0][dt] = __builtin_amdgcn_mfma_f32_16x16x32_f16(pap[0][u], bv.v8, o[0][dt], 0, 0, 0);
                    o[1][dt] = __builtin_amdgcn_mfma_f32_16x16x32_f16(pap[1][u], bv.v8, o[1][dt], 0, 0, 0);
                }
            }
            __builtin_amdgcn_s_setprio(0);
        };

        // ---- one pipeline stage: QK(t) -> PV(t-1) issue -> exp/pack(t) -> o-rescale
        auto stage_fn = [&](int t, int cbr, int cbw,
                            h16x8 (&pap)[2][2], h16x8 (&pan)[2][2]) {
            const int kv0 = t * KBLK;

            // staged regs (tile t+1) -> LDS
            if (t + 1 < nkv) {
                h16* kw = &Kl[cbw][kwoff];
#pragma unroll
                for (int it = 0; it < 2; ++it)
                    *(h16x8*)(kw + it * 32 * KPAD) = pack8(kra[it], krb[it]);
#pragma unroll
                for (int e = 0; e < 4; ++e)
                    *(h16x4*)&vnext_[(vd0 + e) * VPAD + vcol] =
                        pack4(vra[0][e], vra[1][e], vra[2][e], vra[3][e]);
            }
            // issue tile t+2 global loads
            if (t + 2 < nkv) {
                const size_t toff = (size_t)(kv0 + 2 * KBLK) * RSTRIDE;
#pragma unroll
                for (int it = 0; it < 2; ++it) {
                    const float* gp = kbase + toff + (size_t)(32 * it) * RSTRIDE;
                    kra[it] = *(const f32x4*)gp;
                    krb[it] = *(const f32x4*)(gp + 4);
                }
#pragma unroll
                for (int kk = 0; kk < 4; ++kk)
                    vra[kk] = *(const f32x4*)(vbase + toff + (size_t)kk * RSTRIDE);
            }

            const bool do_qk = (kv0 <= wbase + 31);
            const bool do_pv = (t >= 1) && (kv0 - KBLK <= wbase + 31);

            f32x4 sacc[2][4];
            float aval[2] = {1.f, 1.f};
            bool  afl[2]  = {false, false};

            if (do_qk) {
                const h16* Kfb = &Kl[cbr][kfoff];
#pragma unroll
                for (int s2 = 0; s2 < 2; ++s2)
#pragma unroll
                    for (int kt = 0; kt < 4; ++kt) sacc[s2][kt] = f32x4{0.f, 0.f, 0.f, 0.f};
                __builtin_amdgcn_s_setprio(1);
#pragma unroll
                for (int kt = 0; kt < 4; ++kt) {
#pragma unroll
                    for (int dk = 0; dk < 4; ++dk) {
                        h16x8 a = *(const h16x8*)(Kfb + kt * 16 * KPAD + dk * 32);
                        sacc[0][kt] = __builtin_amdgcn_mfma_f32_16x16x32_f16(a, qf[0][dk], sacc[0][kt], 0, 0, 0);
                        sacc[1][kt] = __builtin_amdgcn_mfma_f32_16x16x32_f16(a, qf[1][dk], sacc[1][kt], 0, 0, 0);
                    }
                }
                __builtin_amdgcn_s_setprio(0);

                float vmax[2] = {NEGINF, NEGINF};
                if (kv0 + 63 <= wbase) {       // interior for both strips
#pragma unroll
                    for (int s2 = 0; s2 < 2; ++s2)
#pragma unroll
                        for (int kt = 0; kt < 4; ++kt)
#pragma unroll
                            for (int r = 0; r < 4; ++r) vmax[s2] = fmaxf(vmax[s2], sacc[s2][kt][r]);
                } else {
#pragma unroll
                    for (int s2 = 0; s2 < 2; ++s2) {
                        const int qrow = wbase + s2 * 16 + lc;
#pragma unroll
                        for (int kt = 0; kt < 4; ++kt)
#pragma unroll
                            for (int r = 0; r < 4; ++r) {
                                const int key = kv0 + 16 * kt + 4 * lg + r;
                                float sv = (key <= qrow) ? sacc[s2][kt][r] : NEGINF;
                                sacc[s2][kt][r] = sv;
                                vmax[s2] = fmaxf(vmax[s2], sv);
                            }
                    }
                }
#pragma unroll
                for (int s2 = 0; s2 < 2; ++s2) {
                    afl[s2] = __any(vmax[s2] > mreg[s2] + DEFER_THR);
                    if (afl[s2]) {
                        float rmax = fmaxf(vmax[s2], __shfl_xor(vmax[s2], 16, 64));
                        rmax = fmaxf(rmax, __shfl_xor(rmax, 32, 64));
                        const float mnew = fmaxf(mreg[s2], rmax);
                        aval[s2] = __builtin_amdgcn_exp2f(mreg[s2] - mnew);
                        mreg[s2] = mnew;
                        lsum[s2] *= aval[s2];
                    }
                }
            }

            // ---- PV(t-1): issued before exp so its MFMAs cover the VALU below (T15)
            if (do_pv) pv_fn(vprev_ + vfoff, pap);

            if (do_qk) {
#pragma unroll
                for (int s2 = 0; s2 < 2; ++s2) {
                    float psum = 0.f;
#pragma unroll
                    for (int kt = 0; kt < 4; ++kt)
#pragma unroll
                        for (int r = 0; r < 4; ++r) {
                            const float e = __builtin_amdgcn_exp2f(sacc[s2][kt][r] - mreg[s2]);
                            sacc[s2][kt][r] = e;
                            psum += e;
                        }
                    lsum[s2] += psum;
#pragma unroll
                    for (int u = 0; u < 2; ++u)
                        pan[s2][u] = pack8(sacc[s2][2 * u], sacc[s2][2 * u + 1]);
                }
                // deferred o-rescale: after PV(t-1) has been added (m(t-1)-scale)
#pragma unroll
                for (int s2 = 0; s2 < 2; ++s2) {
                    if (afl[s2]) {
#pragma unroll
                        for (int r = 0; r < 4; ++r) {
                            const float ar = __shfl(aval[s2], 4 * lg + r, 64);
#pragma unroll
                            for (int dt = 0; dt < 8; ++dt) o[s2][dt][r] *= ar;
                        }
                    }
                }
            }
            __syncthreads();   // single barrier per stage
            h16* tmp = vprev_; vprev_ = vcurr_; vcurr_ = vnext_; vnext_ = tmp;
        };

        for (int tt = 0; tt < nkv; tt += 2) {
            stage_fn(tt,     0, 1, paA, paB);
            stage_fn(tt + 1, 1, 0, paB, paA);
        }

        // ---- drain: last tile's PV (waves whose t_last == nkv-1; pa in paA)
        if ((nkv - 1) * KBLK <= wbase + 31)
            pv_fn(vprev_ + vfoff, paA);

        // ---- epilogue
#pragma unroll
        for (int s2 = 0; s2 < 2; ++s2) {
            float ls = lsum[s2];
            ls += __shfl_xor(ls, 16, 64);
            ls += __shfl_xor(ls, 32, 64);
#pragma unroll
            for (int r = 0; r < 4; ++r) {
                const float lr  = __shfl(ls, 4 * lg + r, 64);
                const float inv = 1.0f / lr;
                const int qrow  = wbase + s2 * 16 + 4 * lg + r;
                float* op = Out + (size_t)qrow * RSTRIDE + bhoff + lc;
#pragma unroll
                for (int dt = 0; dt < 8; ++dt) op[dt * 16] = o[s2][dt][r] * inv;
            }
        }
    } // half
}

extern "C" void kernel_launch(void* const* d_in, const int* in_sizes, int n_in,
                              void* d_out, int out_size, void* d_ws, size_t ws_size,
                              hipStream_t stream) {
    (void)in_sizes; (void)n_in; (void)out_size; (void)d_ws; (void)ws_size;
    const float* Q = (const float*)d_in[0];
    const float* K = (const float*)d_in[1];
    const float* V = (const float*)d_in[2];
    float* O = (float*)d_out;
    fa_fwd_kernel<<<dim3(NQT / 2, 64), 512, 0, stream>>>(Q, K, V, O);
}

// Round 11
// 123.030 us; speedup vs baseline: 1.0874x; 1.0194x over previous
//
#include <hip/hip_runtime.h>

typedef _Float16 h16;
typedef _Float16 h16x4 __attribute__((ext_vector_type(4)));
typedef _Float16 h16x8 __attribute__((ext_vector_type(8)));
typedef __fp16 fp16x2 __attribute__((ext_vector_type(2)));   // cvt_pkrtz native type
typedef float f32x4 __attribute__((ext_vector_type(4)));

#define SEQ 2048
#define RSTRIDE 8192   // b*h*d = 4*16*128
#define QTILE 256
#define NQT (SEQ / QTILE)   // 8
#define KBLK 64
#define KPAD 136       // K LDS row stride (halves)
#define VPAD 72        // Vt LDS row stride (halves)
#define DEFER_THR 8.0f

static __device__ __forceinline__ h16x8 pack8(f32x4 a, f32x4 b) {
    union { fp16x2 h2[4]; h16x8 h8; } u;
    u.h2[0] = __builtin_amdgcn_cvt_pkrtz(a[0], a[1]);
    u.h2[1] = __builtin_amdgcn_cvt_pkrtz(a[2], a[3]);
    u.h2[2] = __builtin_amdgcn_cvt_pkrtz(b[0], b[1]);
    u.h2[3] = __builtin_amdgcn_cvt_pkrtz(b[2], b[3]);
    return u.h8;
}

static __device__ __forceinline__ h16x4 pack4(float x0, float x1, float x2, float x3) {
    union { fp16x2 h2[2]; h16x4 h4; } u;
    u.h2[0] = __builtin_amdgcn_cvt_pkrtz(x0, x1);
    u.h2[1] = __builtin_amdgcn_cvt_pkrtz(x2, x3);
    return u.h4;
}

__global__ __launch_bounds__(512, 2)
void fa_fwd_kernel(const float* __restrict__ Qg, const float* __restrict__ Kg,
                   const float* __restrict__ Vg, float* __restrict__ Out)
{
    __shared__ __attribute__((aligned(16))) h16 Kl[2][KBLK * KPAD];   // [key][d]
    __shared__ __attribute__((aligned(16))) h16 Vt[3][128 * VPAD];    // [d][key^swz], triple buf

    // grid (4,64); XCD x owns bh {8x..8x+7}; causal pairs (bx, 7-bx) in-block
    const int lin = (int)blockIdx.x + 4 * (int)blockIdx.y;
    const int bx  = (lin >> 3) & 3;               // 0..3
    const int bh  = 8 * (lin & 7) + (lin >> 5);   // 0..63
    const int tid  = threadIdx.x;   // 0..511 (8 waves)
    const int wave = tid >> 6;
    const int role = wave >> 2;     // waves w and w+4 share a SIMD -> opposite roles
    const int lane = tid & 63;
    const int lg   = lane >> 4;
    const int lc   = lane & 15;
    const size_t bhoff = (size_t)bh * 128;
    const float NEGINF = -__builtin_inff();
    const float SL = 0.08838834764831845f * 1.4426950408889634f;  // (1/sqrt(128))*log2(e)

    // ---- K staging geometry
    const int krow = tid >> 4;            // 0..31 (+32*it)
    const int kd0  = (tid & 15) * 8;
    const float* kbase = Kg + (size_t)krow * RSTRIDE + bhoff + kd0;
    const int kwoff = krow * KPAD + kd0;

    // ---- V staging geometry
    const int vkey0 = 4 * (tid >> 5);     // 0..60
    const int vd0   = 4 * (tid & 31);     // 0..124
    const int vcol  = vkey0 ^ (4 * (tid & 15));
    const float* vbase = Vg + (size_t)vkey0 * RSTRIDE + bhoff + vd0;

    // ---- per-lane LDS fragment bases
    const int kfoff = lc * KPAD + lg * 8;                      // + kt*16*KPAD + dk*32
    const int vfoff = lc * VPAD + ((4 * lg) ^ (4 * (lc >> 2)));// + dt*16*VPAD + 16*((2u+s)^(dt&3))

    f32x4 kra[2], krb[2], vra[4];   // prefetch registers (T14)

    for (int half = 0; half < 2; ++half) {
        const int qt = half ? (NQT - 1 - bx) : bx;
        const int q0 = qt * QTILE;
        const int wbase = q0 + wave * 32;    // wave's 32 q-rows (2 fused strips)

        // ---- Q fragments, pre-scaled
        h16x8 qf[2][4];
#pragma unroll
        for (int s2 = 0; s2 < 2; ++s2) {
            const int qrow = wbase + s2 * 16 + lc;
            const float* qp = Qg + (size_t)qrow * RSTRIDE + bhoff + lg * 8;
#pragma unroll
            for (int dk = 0; dk < 4; ++dk) {
                f32x4 a = *(const f32x4*)(qp + dk * 32);
                f32x4 b2 = *(const f32x4*)(qp + dk * 32 + 4);
#pragma unroll
                for (int j = 0; j < 4; ++j) { a[j] *= SL; b2[j] *= SL; }
                qf[s2][dk] = pack8(a, b2);
            }
        }

        f32x4 o[2][8];
#pragma unroll
        for (int s2 = 0; s2 < 2; ++s2)
#pragma unroll
            for (int dt = 0; dt < 8; ++dt) o[s2][dt] = f32x4{0.f, 0.f, 0.f, 0.f};
        float mreg[2] = {NEGINF, NEGINF};
        float lsum[2] = {0.f, 0.f};

        h16x8 paA[2][2], paB[2][2];      // static double-buffered P fragments
#pragma unroll
        for (int s2 = 0; s2 < 2; ++s2)
#pragma unroll
            for (int u = 0; u < 2; ++u) paA[s2][u] = h16x8{0,0,0,0,0,0,0,0};

        const int nkv = 4 * (qt + 1);    // always even

        h16* vprev_ = Vt[2];   // tile t-1 (garbage at t=0; do_pv=false)
        h16* vcurr_ = Vt[0];   // tile t
        h16* vnext_ = Vt[1];   // tile t+1 (write target)

        // ---- prologue: load t0 -> regs
#pragma unroll
        for (int it = 0; it < 2; ++it) {
            const float* gp = kbase + (size_t)(32 * it) * RSTRIDE;
            kra[it] = *(const f32x4*)gp;
            krb[it] = *(const f32x4*)(gp + 4);
        }
#pragma unroll
        for (int kk = 0; kk < 4; ++kk)
            vra[kk] = *(const f32x4*)(vbase + (size_t)kk * RSTRIDE);
        __syncthreads();   // previous half fully done (incl. drain PV) before overwrite
        {
            h16* kw = &Kl[0][kwoff];
#pragma unroll
            for (int it = 0; it < 2; ++it)
                *(h16x8*)(kw + it * 32 * KPAD) = pack8(kra[it], krb[it]);
#pragma unroll
            for (int e = 0; e < 4; ++e)
                *(h16x4*)&vcurr_[(vd0 + e) * VPAD + vcol] =
                    pack4(vra[0][e], vra[1][e], vra[2][e], vra[3][e]);
        }
        if (nkv > 1) {
            const size_t toff = (size_t)KBLK * RSTRIDE;
#pragma unroll
            for (int it = 0; it < 2; ++it) {
                const float* gp = kbase + toff + (size_t)(32 * it) * RSTRIDE;
                kra[it] = *(const f32x4*)gp;
                krb[it] = *(const f32x4*)(gp + 4);
            }
#pragma unroll
            for (int kk = 0; kk < 4; ++kk)
                vra[kk] = *(const f32x4*)(vbase + toff + (size_t)kk * RSTRIDE);
        }
        __syncthreads();   // buf0 visible

        // ---- PV: 1 V-fragment load -> 2 MFMAs (both strips)
        auto pv_fn = [&](const h16* Vfb, h16x8 (&pap)[2][2]) {
            __builtin_amdgcn_s_setprio(1);
#pragma unroll
            for (int dt = 0; dt < 8; ++dt) {
#pragma unroll
                for (int u = 0; u < 2; ++u) {
                    union { h16x8 v8; h16x4 v4[2]; } bv;
                    bv.v4[0] = *(const h16x4*)(Vfb + dt * 16 * VPAD + 16 * ((2 * u + 0) ^ (dt & 3)));
                    bv.v4[1] = *(const h16x4*)(Vfb + dt * 16 * VPAD + 16 * ((2 * u + 1) ^ (dt & 3)));
                    o[0][dt] = __builtin_amdgcn_mfma_f32_16x16x32_f16(pap[0][u], bv.v8, o[0][dt], 0, 0, 0);
                    o[1][dt] = __builtin_amdgcn_mfma_f32_16x16x32_f16(pap[1][u], bv.v8, o[1][dt], 0, 0, 0);
                }
            }
            __builtin_amdgcn_s_setprio(0);
        };

        // ---- QK + softmax (no o-rescale; sacc dies here). Sets pan, aval, afl.
        auto qksm_fn = [&](int kv0, int cbr, h16x8 (&pan)[2][2],
                           float (&aval)[2], bool (&afl)[2]) {
            const h16* Kfb = &Kl[cbr][kfoff];
            f32x4 sacc[2][4];
#pragma unroll
            for (int s2 = 0; s2 < 2; ++s2)
#pragma unroll
                for (int kt = 0; kt < 4; ++kt) sacc[s2][kt] = f32x4{0.f, 0.f, 0.f, 0.f};
            __builtin_amdgcn_s_setprio(1);
#pragma unroll
            for (int kt = 0; kt < 4; ++kt) {
#pragma unroll
                for (int dk = 0; dk < 4; ++dk) {
                    h16x8 a = *(const h16x8*)(Kfb + kt * 16 * KPAD + dk * 32);
                    sacc[0][kt] = __builtin_amdgcn_mfma_f32_16x16x32_f16(a, qf[0][dk], sacc[0][kt], 0, 0, 0);
                    sacc[1][kt] = __builtin_amdgcn_mfma_f32_16x16x32_f16(a, qf[1][dk], sacc[1][kt], 0, 0, 0);
                }
            }
            __builtin_amdgcn_s_setprio(0);

            float vmax[2] = {NEGINF, NEGINF};
            if (kv0 + 63 <= wbase) {       // interior for both strips
#pragma unroll
                for (int s2 = 0; s2 < 2; ++s2)
#pragma unroll
                    for (int kt = 0; kt < 4; ++kt)
#pragma unroll
                        for (int r = 0; r < 4; ++r) vmax[s2] = fmaxf(vmax[s2], sacc[s2][kt][r]);
            } else {
#pragma unroll
                for (int s2 = 0; s2 < 2; ++s2) {
                    const int qrow = wbase + s2 * 16 + lc;
#pragma unroll
                    for (int kt = 0; kt < 4; ++kt)
#pragma unroll
                        for (int r = 0; r < 4; ++r) {
                            const int key = kv0 + 16 * kt + 4 * lg + r;
                            float sv = (key <= qrow) ? sacc[s2][kt][r] : NEGINF;
                            sacc[s2][kt][r] = sv;
                            vmax[s2] = fmaxf(vmax[s2], sv);
                        }
                }
            }
#pragma unroll
            for (int s2 = 0; s2 < 2; ++s2) {
                afl[s2] = __any(vmax[s2] > mreg[s2] + DEFER_THR);
                if (afl[s2]) {
                    float rmax = fmaxf(vmax[s2], __shfl_xor(vmax[s2], 16, 64));
                    rmax = fmaxf(rmax, __shfl_xor(rmax, 32, 64));
                    const float mnew = fmaxf(mreg[s2], rmax);
                    aval[s2] = __builtin_amdgcn_exp2f(mreg[s2] - mnew);
                    mreg[s2] = mnew;
                    lsum[s2] *= aval[s2];
                }
                float psum = 0.f;
#pragma unroll
                for (int kt = 0; kt < 4; ++kt)
#pragma unroll
                    for (int r = 0; r < 4; ++r) {
                        const float e = __builtin_amdgcn_exp2f(sacc[s2][kt][r] - mreg[s2]);
                        sacc[s2][kt][r] = e;
                        psum += e;
                    }
                lsum[s2] += psum;
#pragma unroll
                for (int u = 0; u < 2; ++u)
                    pan[s2][u] = pack8(sacc[s2][2 * u], sacc[s2][2 * u + 1]);
            }
        };

        // ---- one stage; role-staggered order so SIMD partners overlap pipes
        auto stage_fn = [&](int t, int cbr, int cbw,
                            h16x8 (&pap)[2][2], h16x8 (&pan)[2][2]) {
            const int kv0 = t * KBLK;

            if (t + 1 < nkv) {
                h16* kw = &Kl[cbw][kwoff];
#pragma unroll
                for (int it = 0; it < 2; ++it)
                    *(h16x8*)(kw + it * 32 * KPAD) = pack8(kra[it], krb[it]);
#pragma unroll
                for (int e = 0; e < 4; ++e)
                    *(h16x4*)&vnext_[(vd0 + e) * VPAD + vcol] =
                        pack4(vra[0][e], vra[1][e], vra[2][e], vra[3][e]);
            }
            if (t + 2 < nkv) {
                const size_t toff = (size_t)(kv0 + 2 * KBLK) * RSTRIDE;
#pragma unroll
                for (int it = 0; it < 2; ++it) {
                    const float* gp = kbase + toff + (size_t)(32 * it) * RSTRIDE;
                    kra[it] = *(const f32x4*)gp;
                    krb[it] = *(const f32x4*)(gp + 4);
                }
#pragma unroll
                for (int kk = 0; kk < 4; ++kk)
                    vra[kk] = *(const f32x4*)(vbase + toff + (size_t)kk * RSTRIDE);
            }

            const bool do_qk = (kv0 <= wbase + 31);
            const bool do_pv = (t >= 1) && (kv0 - KBLK <= wbase + 31);

            float aval[2] = {1.f, 1.f};
            bool  afl[2]  = {false, false};

            if (role) {                      // odd role: PV first
                if (do_pv) pv_fn(vprev_ + vfoff, pap);
            }
            if (do_qk) qksm_fn(kv0, cbr, pan, aval, afl);
            if (!role) {                     // even role: PV after softmax
                if (do_pv) pv_fn(vprev_ + vfoff, pap);
            }
            if (do_qk) {
#pragma unroll
                for (int s2 = 0; s2 < 2; ++s2) {
                    if (afl[s2]) {
#pragma unroll
                        for (int r = 0; r < 4; ++r) {
                            const float ar = __shfl(aval[s2], 4 * lg + r, 64);
#pragma unroll
                            for (int dt = 0; dt < 8; ++dt) o[s2][dt][r] *= ar;
                        }
                    }
                }
            }
            __syncthreads();
            h16* tmp = vprev_; vprev_ = vcurr_; vcurr_ = vnext_; vnext_ = tmp;
        };

        for (int tt = 0; tt < nkv; tt += 2) {
            stage_fn(tt,     0, 1, paA, paB);
            stage_fn(tt + 1, 1, 0, paB, paA);
        }

        // ---- drain: last tile's PV (pa in paA after even nkv)
        if ((nkv - 1) * KBLK <= wbase + 31)
            pv_fn(vprev_ + vfoff, paA);

        // ---- epilogue
#pragma unroll
        for (int s2 = 0; s2 < 2; ++s2) {
            float ls = lsum[s2];
            ls += __shfl_xor(ls, 16, 64);
            ls += __shfl_xor(ls, 32, 64);
#pragma unroll
            for (int r = 0; r < 4; ++r) {
                const float lr  = __shfl(ls, 4 * lg + r, 64);
                const float inv = 1.0f / lr;
                const int qrow  = wbase + s2 * 16 + 4 * lg + r;
                float* op = Out + (size_t)qrow * RSTRIDE + bhoff + lc;
#pragma unroll
                for (int dt = 0; dt < 8; ++dt) op[dt * 16] = o[s2][dt][r] * inv;
            }
        }
    } // half
}

extern "C" void kernel_launch(void* const* d_in, const int* in_sizes, int n_in,
                              void* d_out, int out_size, void* d_ws, size_t ws_size,
                              hipStream_t stream) {
    (void)in_sizes; (void)n_in; (void)out_size; (void)d_ws; (void)ws_size;
    const float* Q = (const float*)d_in[0];
    const float* K = (const float*)d_in[1];
    const float* V = (const float*)d_in[2];
    float* O = (float*)d_out;
    fa_fwd_kernel<<<dim3(NQT / 2, 64), 512, 0, stream>>>(Q, K, V, O);
}

// Round 12
// 111.990 us; speedup vs baseline: 1.1946x; 1.0986x over previous
//
#include <hip/hip_runtime.h>

typedef _Float16 h16;
typedef _Float16 h16x4 __attribute__((ext_vector_type(4)));
typedef _Float16 h16x8 __attribute__((ext_vector_type(8)));
typedef __fp16 fp16x2 __attribute__((ext_vector_type(2)));   // cvt_pkrtz native type
typedef float f32x4 __attribute__((ext_vector_type(4)));

#define SEQ 2048
#define RSTRIDE 8192   // b*h*d = 4*16*128
#define QTILE 256
#define NQT (SEQ / QTILE)   // 8
#define KBLK 64
#define KPAD 136       // K LDS row stride (halves)
#define VPAD 72        // Vt LDS row stride (halves)
#define DEFER_THR 8.0f

static __device__ __forceinline__ h16x8 pack8(f32x4 a, f32x4 b) {
    union { fp16x2 h2[4]; h16x8 h8; } u;
    u.h2[0] = __builtin_amdgcn_cvt_pkrtz(a[0], a[1]);
    u.h2[1] = __builtin_amdgcn_cvt_pkrtz(a[2], a[3]);
    u.h2[2] = __builtin_amdgcn_cvt_pkrtz(b[0], b[1]);
    u.h2[3] = __builtin_amdgcn_cvt_pkrtz(b[2], b[3]);
    return u.h8;
}

static __device__ __forceinline__ h16x4 pack4(float x0, float x1, float x2, float x3) {
    union { fp16x2 h2[2]; h16x4 h4; } u;
    u.h2[0] = __builtin_amdgcn_cvt_pkrtz(x0, x1);
    u.h2[1] = __builtin_amdgcn_cvt_pkrtz(x2, x3);
    return u.h4;
}

__global__ __launch_bounds__(512, 2)
void fa_fwd_kernel(const float* __restrict__ Qg, const float* __restrict__ Kg,
                   const float* __restrict__ Vg, float* __restrict__ Out)
{
    __shared__ __attribute__((aligned(16))) h16 Kl[2][KBLK * KPAD];   // [key][d]
    __shared__ __attribute__((aligned(16))) h16 Vt[2][128 * VPAD];    // [d][key^swz]

    // XCD-aware remap (256 blocks, 1/CU): XCD x owns bh in {8x..8x+7}
    const int lin = (int)blockIdx.x + 4 * (int)blockIdx.y;   // hw XCD = lin % 8
    const int bx  = (lin >> 3) & 3;               // 0..3, pairs (bx, 7-bx)
    const int bh  = 8 * (lin & 7) + (lin >> 5);   // 0..63
    const int tid  = threadIdx.x;   // 0..511 (8 waves)
    const int wave = tid >> 6;
    const int lane = tid & 63;
    const int lg   = lane >> 4;
    const int lc   = lane & 15;
    const size_t bhoff = (size_t)bh * 128;
    const float NEGINF = -__builtin_inff();
    const float SL = 0.08838834764831845f * 1.4426950408889634f;  // (1/sqrt(128))*log2(e)

    // ---- K staging geometry
    const int krow = tid >> 4;            // 0..31 (+32*it)
    const int kd0  = (tid & 15) * 8;
    const float* kbase = Kg + (size_t)krow * RSTRIDE + bhoff + kd0;
    const int kwoff = krow * KPAD + kd0;

    // ---- V staging geometry
    const int vkey0 = 4 * (tid >> 5);     // 0..60
    const int vd0   = 4 * (tid & 31);     // 0..124
    const int vcol  = vkey0 ^ (4 * (tid & 15));
    const float* vbase = Vg + (size_t)vkey0 * RSTRIDE + bhoff + vd0;

    // ---- per-lane LDS fragment bases
    const int kfoff = lc * KPAD + lg * 8;                      // + kt*16*KPAD + dk*32
    const int vfoff = lc * VPAD + ((4 * lg) ^ (4 * (lc >> 2)));// + dt*16*VPAD + 16*((2u+s)^(dt&3))

    // ones B-fragment for the P.1 row-sum MFMA
    const h16x8 vones = h16x8{(h16)1.f,(h16)1.f,(h16)1.f,(h16)1.f,
                              (h16)1.f,(h16)1.f,(h16)1.f,(h16)1.f};

    f32x4 kra[2], krb[2], vra[4];   // prefetch registers (T14)

    for (int half = 0; half < 2; ++half) {
        const int qt = half ? (NQT - 1 - bx) : bx;
        const int q0 = qt * QTILE;
        const int wbase = q0 + wave * 32;    // wave's 32 q-rows (2 fused strips)

        // ---- Q fragments, pre-scaled
        h16x8 qf[2][4];
#pragma unroll
        for (int s2 = 0; s2 < 2; ++s2) {
            const int qrow = wbase + s2 * 16 + lc;
            const float* qp = Qg + (size_t)qrow * RSTRIDE + bhoff + lg * 8;
#pragma unroll
            for (int dk = 0; dk < 4; ++dk) {
                f32x4 a = *(const f32x4*)(qp + dk * 32);
                f32x4 b2 = *(const f32x4*)(qp + dk * 32 + 4);
#pragma unroll
                for (int j = 0; j < 4; ++j) { a[j] *= SL; b2[j] *= SL; }
                qf[s2][dk] = pack8(a, b2);
            }
        }

        f32x4 o[2][8];
#pragma unroll
        for (int s2 = 0; s2 < 2; ++s2)
#pragma unroll
            for (int dt = 0; dt < 8; ++dt) o[s2][dt] = f32x4{0.f, 0.f, 0.f, 0.f};
        float mreg[2] = {NEGINF, NEGINF};
        f32x4 lacc[2];                       // row-sums via ones-MFMA: lacc[s2][r] = sum row 4lg+r
        lacc[0] = f32x4{0.f, 0.f, 0.f, 0.f};
        lacc[1] = f32x4{0.f, 0.f, 0.f, 0.f};

        const int nkv = 4 * (qt + 1);

        // ---- prologue
#pragma unroll
        for (int it = 0; it < 2; ++it) {
            const float* gp = kbase + (size_t)(32 * it) * RSTRIDE;
            kra[it] = *(const f32x4*)gp;
            krb[it] = *(const f32x4*)(gp + 4);
        }
#pragma unroll
        for (int kk = 0; kk < 4; ++kk)
            vra[kk] = *(const f32x4*)(vbase + (size_t)kk * RSTRIDE);
        __syncthreads();
        {
            h16* kw = &Kl[0][kwoff];
#pragma unroll
            for (int it = 0; it < 2; ++it)
                *(h16x8*)(kw + it * 32 * KPAD) = pack8(kra[it], krb[it]);
#pragma unroll
            for (int e = 0; e < 4; ++e)
                *(h16x4*)&Vt[0][(vd0 + e) * VPAD + vcol] =
                    pack4(vra[0][e], vra[1][e], vra[2][e], vra[3][e]);
        }
        if (nkv > 1) {
            const size_t toff = (size_t)KBLK * RSTRIDE;
#pragma unroll
            for (int it = 0; it < 2; ++it) {
                const float* gp = kbase + toff + (size_t)(32 * it) * RSTRIDE;
                kra[it] = *(const f32x4*)gp;
                krb[it] = *(const f32x4*)(gp + 4);
            }
#pragma unroll
            for (int kk = 0; kk < 4; ++kk)
                vra[kk] = *(const f32x4*)(vbase + toff + (size_t)kk * RSTRIDE);
        }
        __syncthreads();

        for (int t = 0; t < nkv; ++t) {
            const int kv0 = t * KBLK;
            const int cb = t & 1;

            if (t + 1 < nkv) {
                h16* kw = &Kl[cb ^ 1][kwoff];
#pragma unroll
                for (int it = 0; it < 2; ++it)
                    *(h16x8*)(kw + it * 32 * KPAD) = pack8(kra[it], krb[it]);
#pragma unroll
                for (int e = 0; e < 4; ++e)
                    *(h16x4*)&Vt[cb ^ 1][(vd0 + e) * VPAD + vcol] =
                        pack4(vra[0][e], vra[1][e], vra[2][e], vra[3][e]);
            }
            if (t + 2 < nkv) {
                const size_t toff = (size_t)(kv0 + 2 * KBLK) * RSTRIDE;
#pragma unroll
                for (int it = 0; it < 2; ++it) {
                    const float* gp = kbase + toff + (size_t)(32 * it) * RSTRIDE;
                    kra[it] = *(const f32x4*)gp;
                    krb[it] = *(const f32x4*)(gp + 4);
                }
#pragma unroll
                for (int kk = 0; kk < 4; ++kk)
                    vra[kk] = *(const f32x4*)(vbase + toff + (size_t)kk * RSTRIDE);
            }

            // ---- fused compute: both strips share every LDS fragment load
            if (kv0 <= wbase + 31) {           // wave-uniform
                const h16* Kfb = &Kl[cb][kfoff];
                const h16* Vfb = &Vt[cb][vfoff];

                // S^T = K . Q^T for both strips: 1 load -> 2 MFMAs
                f32x4 sacc[2][4];
#pragma unroll
                for (int s2 = 0; s2 < 2; ++s2)
#pragma unroll
                    for (int kt = 0; kt < 4; ++kt) sacc[s2][kt] = f32x4{0.f, 0.f, 0.f, 0.f};
                __builtin_amdgcn_s_setprio(1);
#pragma unroll
                for (int kt = 0; kt < 4; ++kt) {
#pragma unroll
                    for (int dk = 0; dk < 4; ++dk) {
                        h16x8 a = *(const h16x8*)(Kfb + kt * 16 * KPAD + dk * 32);
                        sacc[0][kt] = __builtin_amdgcn_mfma_f32_16x16x32_f16(a, qf[0][dk], sacc[0][kt], 0, 0, 0);
                        sacc[1][kt] = __builtin_amdgcn_mfma_f32_16x16x32_f16(a, qf[1][dk], sacc[1][kt], 0, 0, 0);
                    }
                }
                __builtin_amdgcn_s_setprio(0);

                // masks + per-lane max (max3-fusable trees on interior tiles)
                float vmax[2];
                if (kv0 + 63 <= wbase) {       // interior for both strips
#pragma unroll
                    for (int s2 = 0; s2 < 2; ++s2) {
                        const float a0 = fmaxf(fmaxf(sacc[s2][0][0], sacc[s2][0][1]), sacc[s2][0][2]);
                        const float a1 = fmaxf(fmaxf(sacc[s2][0][3], sacc[s2][1][0]), sacc[s2][1][1]);
                        const float a2 = fmaxf(fmaxf(sacc[s2][1][2], sacc[s2][1][3]), sacc[s2][2][0]);
                        const float a3 = fmaxf(fmaxf(sacc[s2][2][1], sacc[s2][2][2]), sacc[s2][2][3]);
                        const float a4 = fmaxf(fmaxf(sacc[s2][3][0], sacc[s2][3][1]), sacc[s2][3][2]);
                        const float b0 = fmaxf(fmaxf(a0, a1), a2);
                        const float b1 = fmaxf(fmaxf(a3, a4), sacc[s2][3][3]);
                        vmax[s2] = fmaxf(b0, b1);
                    }
                } else {
#pragma unroll
                    for (int s2 = 0; s2 < 2; ++s2) {
                        vmax[s2] = NEGINF;
                        const int qrow = wbase + s2 * 16 + lc;
#pragma unroll
                        for (int kt = 0; kt < 4; ++kt)
#pragma unroll
                            for (int r = 0; r < 4; ++r) {
                                const int key = kv0 + 16 * kt + 4 * lg + r;
                                float sv = (key <= qrow) ? sacc[s2][kt][r] : NEGINF;
                                sacc[s2][kt][r] = sv;
                                vmax[s2] = fmaxf(vmax[s2], sv);
                            }
                    }
                }

                // per-strip online softmax (T13 defer-max) + P fragments + P.1 rowsum
                h16x8 pa[2][2];
#pragma unroll
                for (int s2 = 0; s2 < 2; ++s2) {
                    if (__any(vmax[s2] > mreg[s2] + DEFER_THR)) {
                        float rmax = fmaxf(vmax[s2], __shfl_xor(vmax[s2], 16, 64));
                        rmax = fmaxf(rmax, __shfl_xor(rmax, 32, 64));
                        const float mnew  = fmaxf(mreg[s2], rmax);
                        const float alpha = __builtin_amdgcn_exp2f(mreg[s2] - mnew);
                        mreg[s2] = mnew;
#pragma unroll
                        for (int r = 0; r < 4; ++r) {
                            const float ar = __shfl(alpha, 4 * lg + r, 64);
                            lacc[s2][r] *= ar;
#pragma unroll
                            for (int dt = 0; dt < 8; ++dt) o[s2][dt][r] *= ar;
                        }
                    }
#pragma unroll
                    for (int kt = 0; kt < 4; ++kt)
#pragma unroll
                        for (int r = 0; r < 4; ++r)
                            sacc[s2][kt][r] = __builtin_amdgcn_exp2f(sacc[s2][kt][r] - mreg[s2]);
#pragma unroll
                    for (int u = 0; u < 2; ++u)
                        pa[s2][u] = pack8(sacc[s2][2 * u], sacc[s2][2 * u + 1]);
                    // row-sums: lacc[r] += sum_k P[4lg+r][k]  (replaces 32 VALU adds)
                    lacc[s2] = __builtin_amdgcn_mfma_f32_16x16x32_f16(pa[s2][0], vones, lacc[s2], 0, 0, 0);
                    lacc[s2] = __builtin_amdgcn_mfma_f32_16x16x32_f16(pa[s2][1], vones, lacc[s2], 0, 0, 0);
                }

                // PV for both strips: 1 fragment load -> 2 MFMAs
                __builtin_amdgcn_s_setprio(1);
#pragma unroll
                for (int dt = 0; dt < 8; ++dt) {
#pragma unroll
                    for (int u = 0; u < 2; ++u) {
                        union { h16x8 v8; h16x4 v4[2]; } bv;
                        bv.v4[0] = *(const h16x4*)(Vfb + dt * 16 * VPAD + 16 * ((2 * u + 0) ^ (dt & 3)));
                        bv.v4[1] = *(const h16x4*)(Vfb + dt * 16 * VPAD + 16 * ((2 * u + 1) ^ (dt & 3)));
                        o[0][dt] = __builtin_amdgcn_mfma_f32_16x16x32_f16(pa[0][u], bv.v8, o[0][dt], 0, 0, 0);
                        o[1][dt] = __builtin_amdgcn_mfma_f32_16x16x32_f16(pa[1][u], bv.v8, o[1][dt], 0, 0, 0);
                    }
                }
                __builtin_amdgcn_s_setprio(0);
            }
            __syncthreads();   // single barrier per tile
        } // kv tiles

        // ---- epilogue: lacc[s2][r] is already the full row-sum for q = wbase+16s2+4lg+r
#pragma unroll
        for (int s2 = 0; s2 < 2; ++s2) {
#pragma unroll
            for (int r = 0; r < 4; ++r) {
                const float inv = 1.0f / lacc[s2][r];
                const int qrow  = wbase + s2 * 16 + 4 * lg + r;
                float* op = Out + (size_t)qrow * RSTRIDE + bhoff + lc;
#pragma unroll
                for (int dt = 0; dt < 8; ++dt) op[dt * 16] = o[s2][dt][r] * inv;
            }
        }
    } // half
}

extern "C" void kernel_launch(void* const* d_in, const int* in_sizes, int n_in,
                              void* d_out, int out_size, void* d_ws, size_t ws_size,
                              hipStream_t stream) {
    (void)in_sizes; (void)n_in; (void)out_size; (void)d_ws; (void)ws_size;
    const float* Q = (const float*)d_in[0];
    const float* K = (const float*)d_in[1];
    const float* V = (const float*)d_in[2];
    float* O = (float*)d_out;
    fa_fwd_kernel<<<dim3(NQT / 2, 64), 512, 0, stream>>>(Q, K, V, O);
}

// Round 13
// 109.428 us; speedup vs baseline: 1.2225x; 1.0234x over previous
//
#include <hip/hip_runtime.h>

typedef _Float16 h16;
typedef _Float16 h16x4 __attribute__((ext_vector_type(4)));
typedef _Float16 h16x8 __attribute__((ext_vector_type(8)));
typedef __fp16 fp16x2 __attribute__((ext_vector_type(2)));   // cvt_pkrtz native type
typedef float f32x4 __attribute__((ext_vector_type(4)));

#define SEQ 2048
#define RSTRIDE 8192   // b*h*d = 4*16*128
#define QTILE 256
#define NQT (SEQ / QTILE)   // 8
#define KBLK 64
#define KPAD 136       // K LDS row stride (halves)
#define VPAD 72        // Vt LDS row stride (halves)
#define DEFER_THR 8.0f

static __device__ __forceinline__ h16x8 pack8(f32x4 a, f32x4 b) {
    union { fp16x2 h2[4]; h16x8 h8; } u;
    u.h2[0] = __builtin_amdgcn_cvt_pkrtz(a[0], a[1]);
    u.h2[1] = __builtin_amdgcn_cvt_pkrtz(a[2], a[3]);
    u.h2[2] = __builtin_amdgcn_cvt_pkrtz(b[0], b[1]);
    u.h2[3] = __builtin_amdgcn_cvt_pkrtz(b[2], b[3]);
    return u.h8;
}

static __device__ __forceinline__ h16x4 pack4(float x0, float x1, float x2, float x3) {
    union { fp16x2 h2[2]; h16x4 h4; } u;
    u.h2[0] = __builtin_amdgcn_cvt_pkrtz(x0, x1);
    u.h2[1] = __builtin_amdgcn_cvt_pkrtz(x2, x3);
    return u.h4;
}

// T4-lite barrier: drain ONLY LDS ops (write visibility), leave register-destined
// global loads (vmcnt) in flight across the barrier. __syncthreads would emit
// s_waitcnt vmcnt(0) lgkmcnt(0) and kill the prefetch pipeline every stage.
static __device__ __forceinline__ void barrier_lgkm() {
    asm volatile("s_waitcnt lgkmcnt(0)" ::: "memory");
    __builtin_amdgcn_s_barrier();
}

__global__ __launch_bounds__(512, 2)
void fa_fwd_kernel(const float* __restrict__ Qg, const float* __restrict__ Kg,
                   const float* __restrict__ Vg, float* __restrict__ Out)
{
    __shared__ __attribute__((aligned(16))) h16 Kl[2][KBLK * KPAD];   // [key][d]
    __shared__ __attribute__((aligned(16))) h16 Vt[2][128 * VPAD];    // [d][key^swz]

    // XCD-aware remap (256 blocks, 1/CU): XCD x owns bh in {8x..8x+7}
    const int lin = (int)blockIdx.x + 4 * (int)blockIdx.y;   // hw XCD = lin % 8
    const int bx  = (lin >> 3) & 3;               // 0..3, pairs (bx, 7-bx)
    const int bh  = 8 * (lin & 7) + (lin >> 5);   // 0..63
    const int tid  = threadIdx.x;   // 0..511 (8 waves)
    const int wave = tid >> 6;
    const int lane = tid & 63;
    const int lg   = lane >> 4;
    const int lc   = lane & 15;
    const size_t bhoff = (size_t)bh * 128;
    const float NEGINF = -__builtin_inff();
    const float SL = 0.08838834764831845f * 1.4426950408889634f;  // (1/sqrt(128))*log2(e)

    // ---- K staging geometry
    const int krow = tid >> 4;            // 0..31 (+32*it)
    const int kd0  = (tid & 15) * 8;
    const float* kbase = Kg + (size_t)krow * RSTRIDE + bhoff + kd0;
    const int kwoff = krow * KPAD + kd0;

    // ---- V staging geometry
    const int vkey0 = 4 * (tid >> 5);     // 0..60
    const int vd0   = 4 * (tid & 31);     // 0..124
    const int vcol  = vkey0 ^ (4 * (tid & 15));
    const float* vbase = Vg + (size_t)vkey0 * RSTRIDE + bhoff + vd0;

    // ---- per-lane LDS fragment bases
    const int kfoff = lc * KPAD + lg * 8;                      // + kt*16*KPAD + dk*32
    const int vfoff = lc * VPAD + ((4 * lg) ^ (4 * (lc >> 2)));// + dt*16*VPAD + 16*((2u+s)^(dt&3))

    // ones B-fragment for the P.1 row-sum MFMA
    const h16x8 vones = h16x8{(h16)1.f,(h16)1.f,(h16)1.f,(h16)1.f,
                              (h16)1.f,(h16)1.f,(h16)1.f,(h16)1.f};

    f32x4 kra[2], krb[2], vra[4];   // prefetch registers (T14)

    for (int half = 0; half < 2; ++half) {
        const int qt = half ? (NQT - 1 - bx) : bx;
        const int q0 = qt * QTILE;
        const int wbase = q0 + wave * 32;    // wave's 32 q-rows (2 fused strips)

        // ---- Q fragments, pre-scaled
        h16x8 qf[2][4];
#pragma unroll
        for (int s2 = 0; s2 < 2; ++s2) {
            const int qrow = wbase + s2 * 16 + lc;
            const float* qp = Qg + (size_t)qrow * RSTRIDE + bhoff + lg * 8;
#pragma unroll
            for (int dk = 0; dk < 4; ++dk) {
                f32x4 a = *(const f32x4*)(qp + dk * 32);
                f32x4 b2 = *(const f32x4*)(qp + dk * 32 + 4);
#pragma unroll
                for (int j = 0; j < 4; ++j) { a[j] *= SL; b2[j] *= SL; }
                qf[s2][dk] = pack8(a, b2);
            }
        }

        f32x4 o[2][8];
#pragma unroll
        for (int s2 = 0; s2 < 2; ++s2)
#pragma unroll
            for (int dt = 0; dt < 8; ++dt) o[s2][dt] = f32x4{0.f, 0.f, 0.f, 0.f};
        float mreg[2] = {NEGINF, NEGINF};
        f32x4 lacc[2];                       // row-sums via ones-MFMA
        lacc[0] = f32x4{0.f, 0.f, 0.f, 0.f};
        lacc[1] = f32x4{0.f, 0.f, 0.f, 0.f};

        const int nkv = 4 * (qt + 1);

        // ---- prologue
#pragma unroll
        for (int it = 0; it < 2; ++it) {
            const float* gp = kbase + (size_t)(32 * it) * RSTRIDE;
            kra[it] = *(const f32x4*)gp;
            krb[it] = *(const f32x4*)(gp + 4);
        }
#pragma unroll
        for (int kk = 0; kk < 4; ++kk)
            vra[kk] = *(const f32x4*)(vbase + (size_t)kk * RSTRIDE);
        barrier_lgkm();   // previous half's LDS reads done before overwrite
        {
            h16* kw = &Kl[0][kwoff];
#pragma unroll
            for (int it = 0; it < 2; ++it)
                *(h16x8*)(kw + it * 32 * KPAD) = pack8(kra[it], krb[it]);
#pragma unroll
            for (int e = 0; e < 4; ++e)
                *(h16x4*)&Vt[0][(vd0 + e) * VPAD + vcol] =
                    pack4(vra[0][e], vra[1][e], vra[2][e], vra[3][e]);
        }
        if (nkv > 1) {
            const size_t toff = (size_t)KBLK * RSTRIDE;
#pragma unroll
            for (int it = 0; it < 2; ++it) {
                const float* gp = kbase + toff + (size_t)(32 * it) * RSTRIDE;
                kra[it] = *(const f32x4*)gp;
                krb[it] = *(const f32x4*)(gp + 4);
            }
#pragma unroll
            for (int kk = 0; kk < 4; ++kk)
                vra[kk] = *(const f32x4*)(vbase + toff + (size_t)kk * RSTRIDE);
        }
        barrier_lgkm();   // buf0 visible; t1 loads stay in flight

        for (int t = 0; t < nkv; ++t) {
            const int kv0 = t * KBLK;
            const int cb = t & 1;

            if (t + 1 < nkv) {
                h16* kw = &Kl[cb ^ 1][kwoff];
#pragma unroll
                for (int it = 0; it < 2; ++it)
                    *(h16x8*)(kw + it * 32 * KPAD) = pack8(kra[it], krb[it]);
#pragma unroll
                for (int e = 0; e < 4; ++e)
                    *(h16x4*)&Vt[cb ^ 1][(vd0 + e) * VPAD + vcol] =
                        pack4(vra[0][e], vra[1][e], vra[2][e], vra[3][e]);
            }
            if (t + 2 < nkv) {
                const size_t toff = (size_t)(kv0 + 2 * KBLK) * RSTRIDE;
#pragma unroll
                for (int it = 0; it < 2; ++it) {
                    const float* gp = kbase + toff + (size_t)(32 * it) * RSTRIDE;
                    kra[it] = *(const f32x4*)gp;
                    krb[it] = *(const f32x4*)(gp + 4);
                }
#pragma unroll
                for (int kk = 0; kk < 4; ++kk)
                    vra[kk] = *(const f32x4*)(vbase + toff + (size_t)kk * RSTRIDE);
            }

            // ---- fused compute: both strips share every LDS fragment load
            if (kv0 <= wbase + 31) {           // wave-uniform
                const h16* Kfb = &Kl[cb][kfoff];
                const h16* Vfb = &Vt[cb][vfoff];

                // S^T = K . Q^T for both strips: 1 load -> 2 MFMAs
                f32x4 sacc[2][4];
#pragma unroll
                for (int s2 = 0; s2 < 2; ++s2)
#pragma unroll
                    for (int kt = 0; kt < 4; ++kt) sacc[s2][kt] = f32x4{0.f, 0.f, 0.f, 0.f};
                __builtin_amdgcn_s_setprio(1);
#pragma unroll
                for (int kt = 0; kt < 4; ++kt) {
#pragma unroll
                    for (int dk = 0; dk < 4; ++dk) {
                        h16x8 a = *(const h16x8*)(Kfb + kt * 16 * KPAD + dk * 32);
                        sacc[0][kt] = __builtin_amdgcn_mfma_f32_16x16x32_f16(a, qf[0][dk], sacc[0][kt], 0, 0, 0);
                        sacc[1][kt] = __builtin_amdgcn_mfma_f32_16x16x32_f16(a, qf[1][dk], sacc[1][kt], 0, 0, 0);
                    }
                }
                __builtin_amdgcn_s_setprio(0);

                // masks + per-lane max (max3-fusable trees on interior tiles)
                float vmax[2];
                if (kv0 + 63 <= wbase) {       // interior for both strips
#pragma unroll
                    for (int s2 = 0; s2 < 2; ++s2) {
                        const float a0 = fmaxf(fmaxf(sacc[s2][0][0], sacc[s2][0][1]), sacc[s2][0][2]);
                        const float a1 = fmaxf(fmaxf(sacc[s2][0][3], sacc[s2][1][0]), sacc[s2][1][1]);
                        const float a2 = fmaxf(fmaxf(sacc[s2][1][2], sacc[s2][1][3]), sacc[s2][2][0]);
                        const float a3 = fmaxf(fmaxf(sacc[s2][2][1], sacc[s2][2][2]), sacc[s2][2][3]);
                        const float a4 = fmaxf(fmaxf(sacc[s2][3][0], sacc[s2][3][1]), sacc[s2][3][2]);
                        const float b0 = fmaxf(fmaxf(a0, a1), a2);
                        const float b1 = fmaxf(fmaxf(a3, a4), sacc[s2][3][3]);
                        vmax[s2] = fmaxf(b0, b1);
                    }
                } else {
#pragma unroll
                    for (int s2 = 0; s2 < 2; ++s2) {
                        vmax[s2] = NEGINF;
                        const int qrow = wbase + s2 * 16 + lc;
#pragma unroll
                        for (int kt = 0; kt < 4; ++kt)
#pragma unroll
                            for (int r = 0; r < 4; ++r) {
                                const int key = kv0 + 16 * kt + 4 * lg + r;
                                float sv = (key <= qrow) ? sacc[s2][kt][r] : NEGINF;
                                sacc[s2][kt][r] = sv;
                                vmax[s2] = fmaxf(vmax[s2], sv);
                            }
                    }
                }

                // per-strip online softmax (T13 defer-max) + P fragments + P.1 rowsum
                h16x8 pa[2][2];
#pragma unroll
                for (int s2 = 0; s2 < 2; ++s2) {
                    if (__any(vmax[s2] > mreg[s2] + DEFER_THR)) {
                        float rmax = fmaxf(vmax[s2], __shfl_xor(vmax[s2], 16, 64));
                        rmax = fmaxf(rmax, __shfl_xor(rmax, 32, 64));
                        const float mnew  = fmaxf(mreg[s2], rmax);
                        const float alpha = __builtin_amdgcn_exp2f(mreg[s2] - mnew);
                        mreg[s2] = mnew;
#pragma unroll
                        for (int r = 0; r < 4; ++r) {
                            const float ar = __shfl(alpha, 4 * lg + r, 64);
                            lacc[s2][r] *= ar;
#pragma unroll
                            for (int dt = 0; dt < 8; ++dt) o[s2][dt][r] *= ar;
                        }
                    }
#pragma unroll
                    for (int kt = 0; kt < 4; ++kt)
#pragma unroll
                        for (int r = 0; r < 4; ++r)
                            sacc[s2][kt][r] = __builtin_amdgcn_exp2f(sacc[s2][kt][r] - mreg[s2]);
#pragma unroll
                    for (int u = 0; u < 2; ++u)
                        pa[s2][u] = pack8(sacc[s2][2 * u], sacc[s2][2 * u + 1]);
                    // row-sums: lacc[r] += sum_k P[4lg+r][k]
                    lacc[s2] = __builtin_amdgcn_mfma_f32_16x16x32_f16(pa[s2][0], vones, lacc[s2], 0, 0, 0);
                    lacc[s2] = __builtin_amdgcn_mfma_f32_16x16x32_f16(pa[s2][1], vones, lacc[s2], 0, 0, 0);
                }

                // PV for both strips: 1 fragment load -> 2 MFMAs
                __builtin_amdgcn_s_setprio(1);
#pragma unroll
                for (int dt = 0; dt < 8; ++dt) {
#pragma unroll
                    for (int u = 0; u < 2; ++u) {
                        union { h16x8 v8; h16x4 v4[2]; } bv;
                        bv.v4[0] = *(const h16x4*)(Vfb + dt * 16 * VPAD + 16 * ((2 * u + 0) ^ (dt & 3)));
                        bv.v4[1] = *(const h16x4*)(Vfb + dt * 16 * VPAD + 16 * ((2 * u + 1) ^ (dt & 3)));
                        o[0][dt] = __builtin_amdgcn_mfma_f32_16x16x32_f16(pa[0][u], bv.v8, o[0][dt], 0, 0, 0);
                        o[1][dt] = __builtin_amdgcn_mfma_f32_16x16x32_f16(pa[1][u], bv.v8, o[1][dt], 0, 0, 0);
                    }
                }
                __builtin_amdgcn_s_setprio(0);
            }
            barrier_lgkm();   // single barrier per tile; global prefetch stays in flight
        } // kv tiles

        // ---- epilogue: lacc[s2][r] is the full row-sum for q = wbase+16s2+4lg+r
#pragma unroll
        for (int s2 = 0; s2 < 2; ++s2) {
#pragma unroll
            for (int r = 0; r < 4; ++r) {
                const float inv = 1.0f / lacc[s2][r];
                const int qrow  = wbase + s2 * 16 + 4 * lg + r;
                float* op = Out + (size_t)qrow * RSTRIDE + bhoff + lc;
#pragma unroll
                for (int dt = 0; dt < 8; ++dt) op[dt * 16] = o[s2][dt][r] * inv;
            }
        }
    } // half
}

extern "C" void kernel_launch(void* const* d_in, const int* in_sizes, int n_in,
                              void* d_out, int out_size, void* d_ws, size_t ws_size,
                              hipStream_t stream) {
    (void)in_sizes; (void)n_in; (void)out_size; (void)d_ws; (void)ws_size;
    const float* Q = (const float*)d_in[0];
    const float* K = (const float*)d_in[1];
    const float* V = (const float*)d_in[2];
    float* O = (float*)d_out;
    fa_fwd_kernel<<<dim3(NQT / 2, 64), 512, 0, stream>>>(Q, K, V, O);
}

// Round 14
// 106.501 us; speedup vs baseline: 1.2561x; 1.0275x over previous
//
#include <hip/hip_runtime.h>

typedef _Float16 h16;
typedef _Float16 h16x4 __attribute__((ext_vector_type(4)));
typedef _Float16 h16x8 __attribute__((ext_vector_type(8)));
typedef __fp16 fp16x2 __attribute__((ext_vector_type(2)));   // cvt_pkrtz native type
typedef float f32x4 __attribute__((ext_vector_type(4)));

#define SEQ 2048
#define RSTRIDE 8192   // b*h*d = 4*16*128
#define QTILE 256
#define NQT (SEQ / QTILE)   // 8
#define KBLK 64
#define KPAD 136       // K LDS row stride (halves): b128 r/w conflict-free in 8-lane groups
#define VPAD 76        // V LDS row stride (halves): 152B = 6 banks/row -> bijective over 16 lanes
#define DEFER_THR 8.0f

static __device__ __forceinline__ h16x8 pack8(f32x4 a, f32x4 b) {
    union { fp16x2 h2[4]; h16x8 h8; } u;
    u.h2[0] = __builtin_amdgcn_cvt_pkrtz(a[0], a[1]);
    u.h2[1] = __builtin_amdgcn_cvt_pkrtz(a[2], a[3]);
    u.h2[2] = __builtin_amdgcn_cvt_pkrtz(b[0], b[1]);
    u.h2[3] = __builtin_amdgcn_cvt_pkrtz(b[2], b[3]);
    return u.h8;
}

static __device__ __forceinline__ h16x4 pack4(float x0, float x1, float x2, float x3) {
    union { fp16x2 h2[2]; h16x4 h4; } u;
    u.h2[0] = __builtin_amdgcn_cvt_pkrtz(x0, x1);
    u.h2[1] = __builtin_amdgcn_cvt_pkrtz(x2, x3);
    return u.h4;
}

// drain ONLY LDS ops before the barrier; register-destined global loads stay in flight
static __device__ __forceinline__ void barrier_lgkm() {
    asm volatile("s_waitcnt lgkmcnt(0)" ::: "memory");
    __builtin_amdgcn_s_barrier();
}

__global__ __launch_bounds__(512, 2)
void fa_fwd_kernel(const float* __restrict__ Qg, const float* __restrict__ Kg,
                   const float* __restrict__ Vg, float* __restrict__ Out)
{
    __shared__ __attribute__((aligned(16))) h16 Kl[2][KBLK * KPAD];   // [key][d]
    __shared__ __attribute__((aligned(16))) h16 Vt[2][128 * VPAD];    // [d][key], linear

    // XCD-aware remap (256 blocks, 1/CU): XCD x owns bh in {8x..8x+7}
    const int lin = (int)blockIdx.x + 4 * (int)blockIdx.y;   // hw XCD = lin % 8
    const int bx  = (lin >> 3) & 3;               // 0..3, pairs (bx, 7-bx)
    const int bh  = 8 * (lin & 7) + (lin >> 5);   // 0..63
    const int tid  = threadIdx.x;   // 0..511 (8 waves)
    const int wave = tid >> 6;
    const int lane = tid & 63;
    const int lg   = lane >> 4;
    const int lc   = lane & 15;
    const size_t bhoff = (size_t)bh * 128;
    const float NEGINF = -__builtin_inff();
    const float SL = 0.08838834764831845f * 1.4426950408889634f;  // (1/sqrt(128))*log2(e)

    // ---- K staging geometry
    const int krow = tid >> 4;            // 0..31 (+32*it)
    const int kd0  = (tid & 15) * 8;
    const float* kbase = Kg + (size_t)krow * RSTRIDE + bhoff + kd0;
    const int kwoff = krow * KPAD + kd0;

    // ---- V staging geometry: key-group XOR-permuted across lanes so the
    // b64 LDS writes are bank-conflict-free (bank = 24*l + 2*(g^(l>>2)): cosets distinct)
    const int vkg   = ((tid >> 5) ^ ((tid & 31) >> 2)) & 15;  // key-group 0..15
    const int vkey0 = 4 * vkg;
    const int vd0   = 4 * (tid & 31);     // 0..124
    const float* vbase = Vg + (size_t)vkey0 * RSTRIDE + bhoff + vd0;

    // ---- per-lane LDS fragment bases
    const int kfoff = lc * KPAD + lg * 8;   // + kt*16*KPAD + dk*32
    const int vfoff = lc * VPAD + 4 * lg;   // + dt*16*VPAD + 32u + 16s  (all immediates)

    // ones B-fragment for the P.1 row-sum MFMA
    const h16x8 vones = h16x8{(h16)1.f,(h16)1.f,(h16)1.f,(h16)1.f,
                              (h16)1.f,(h16)1.f,(h16)1.f,(h16)1.f};

    f32x4 kra[2], krb[2], vra[4];   // prefetch registers (T14)

    for (int half = 0; half < 2; ++half) {
        const int qt = half ? (NQT - 1 - bx) : bx;
        const int q0 = qt * QTILE;
        const int wbase = q0 + wave * 32;    // wave's 32 q-rows (2 fused strips)

        // ---- Q fragments, pre-scaled
        h16x8 qf[2][4];
#pragma unroll
        for (int s2 = 0; s2 < 2; ++s2) {
            const int qrow = wbase + s2 * 16 + lc;
            const float* qp = Qg + (size_t)qrow * RSTRIDE + bhoff + lg * 8;
#pragma unroll
            for (int dk = 0; dk < 4; ++dk) {
                f32x4 a = *(const f32x4*)(qp + dk * 32);
                f32x4 b2 = *(const f32x4*)(qp + dk * 32 + 4);
#pragma unroll
                for (int j = 0; j < 4; ++j) { a[j] *= SL; b2[j] *= SL; }
                qf[s2][dk] = pack8(a, b2);
            }
        }

        f32x4 o[2][8];
#pragma unroll
        for (int s2 = 0; s2 < 2; ++s2)
#pragma unroll
            for (int dt = 0; dt < 8; ++dt) o[s2][dt] = f32x4{0.f, 0.f, 0.f, 0.f};
        float mreg[2] = {NEGINF, NEGINF};
        f32x4 lacc[2];                       // row-sums via ones-MFMA
        lacc[0] = f32x4{0.f, 0.f, 0.f, 0.f};
        lacc[1] = f32x4{0.f, 0.f, 0.f, 0.f};

        const int nkv = 4 * (qt + 1);

        // ---- prologue
#pragma unroll
        for (int it = 0; it < 2; ++it) {
            const float* gp = kbase + (size_t)(32 * it) * RSTRIDE;
            kra[it] = *(const f32x4*)gp;
            krb[it] = *(const f32x4*)(gp + 4);
        }
#pragma unroll
        for (int kk = 0; kk < 4; ++kk)
            vra[kk] = *(const f32x4*)(vbase + (size_t)kk * RSTRIDE);
        barrier_lgkm();   // previous half's LDS reads done before overwrite
        {
            h16* kw = &Kl[0][kwoff];
#pragma unroll
            for (int it = 0; it < 2; ++it)
                *(h16x8*)(kw + it * 32 * KPAD) = pack8(kra[it], krb[it]);
#pragma unroll
            for (int e = 0; e < 4; ++e)
                *(h16x4*)&Vt[0][(vd0 + e) * VPAD + vkey0] =
                    pack4(vra[0][e], vra[1][e], vra[2][e], vra[3][e]);
        }
        if (nkv > 1) {
            const size_t toff = (size_t)KBLK * RSTRIDE;
#pragma unroll
            for (int it = 0; it < 2; ++it) {
                const float* gp = kbase + toff + (size_t)(32 * it) * RSTRIDE;
                kra[it] = *(const f32x4*)gp;
                krb[it] = *(const f32x4*)(gp + 4);
            }
#pragma unroll
            for (int kk = 0; kk < 4; ++kk)
                vra[kk] = *(const f32x4*)(vbase + toff + (size_t)kk * RSTRIDE);
        }
        barrier_lgkm();   // buf0 visible; t1 loads stay in flight

        for (int t = 0; t < nkv; ++t) {
            const int kv0 = t * KBLK;
            const int cb = t & 1;

            if (t + 1 < nkv) {
                h16* kw = &Kl[cb ^ 1][kwoff];
#pragma unroll
                for (int it = 0; it < 2; ++it)
                    *(h16x8*)(kw + it * 32 * KPAD) = pack8(kra[it], krb[it]);
#pragma unroll
                for (int e = 0; e < 4; ++e)
                    *(h16x4*)&Vt[cb ^ 1][(vd0 + e) * VPAD + vkey0] =
                        pack4(vra[0][e], vra[1][e], vra[2][e], vra[3][e]);
            }
            if (t + 2 < nkv) {
                const size_t toff = (size_t)(kv0 + 2 * KBLK) * RSTRIDE;
#pragma unroll
                for (int it = 0; it < 2; ++it) {
                    const float* gp = kbase + toff + (size_t)(32 * it) * RSTRIDE;
                    kra[it] = *(const f32x4*)gp;
                    krb[it] = *(const f32x4*)(gp + 4);
                }
#pragma unroll
                for (int kk = 0; kk < 4; ++kk)
                    vra[kk] = *(const f32x4*)(vbase + toff + (size_t)kk * RSTRIDE);
            }

            // ---- fused compute: both strips share every LDS fragment load
            if (kv0 <= wbase + 31) {           // wave-uniform
                const h16* Kfb = &Kl[cb][kfoff];
                const h16* Vfb = &Vt[cb][vfoff];

                // S^T = K . Q^T for both strips: 1 load -> 2 MFMAs
                f32x4 sacc[2][4];
#pragma unroll
                for (int s2 = 0; s2 < 2; ++s2)
#pragma unroll
                    for (int kt = 0; kt < 4; ++kt) sacc[s2][kt] = f32x4{0.f, 0.f, 0.f, 0.f};
                __builtin_amdgcn_s_setprio(1);
#pragma unroll
                for (int kt = 0; kt < 4; ++kt) {
#pragma unroll
                    for (int dk = 0; dk < 4; ++dk) {
                        h16x8 a = *(const h16x8*)(Kfb + kt * 16 * KPAD + dk * 32);
                        sacc[0][kt] = __builtin_amdgcn_mfma_f32_16x16x32_f16(a, qf[0][dk], sacc[0][kt], 0, 0, 0);
                        sacc[1][kt] = __builtin_amdgcn_mfma_f32_16x16x32_f16(a, qf[1][dk], sacc[1][kt], 0, 0, 0);
                    }
                }
                __builtin_amdgcn_s_setprio(0);

                // masks + per-lane max (max3-fusable trees on interior tiles)
                float vmax[2];
                if (kv0 + 63 <= wbase) {       // interior for both strips
#pragma unroll
                    for (int s2 = 0; s2 < 2; ++s2) {
                        const float a0 = fmaxf(fmaxf(sacc[s2][0][0], sacc[s2][0][1]), sacc[s2][0][2]);
                        const float a1 = fmaxf(fmaxf(sacc[s2][0][3], sacc[s2][1][0]), sacc[s2][1][1]);
                        const float a2 = fmaxf(fmaxf(sacc[s2][1][2], sacc[s2][1][3]), sacc[s2][2][0]);
                        const float a3 = fmaxf(fmaxf(sacc[s2][2][1], sacc[s2][2][2]), sacc[s2][2][3]);
                        const float a4 = fmaxf(fmaxf(sacc[s2][3][0], sacc[s2][3][1]), sacc[s2][3][2]);
                        const float b0 = fmaxf(fmaxf(a0, a1), a2);
                        const float b1 = fmaxf(fmaxf(a3, a4), sacc[s2][3][3]);
                        vmax[s2] = fmaxf(b0, b1);
                    }
                } else {
#pragma unroll
                    for (int s2 = 0; s2 < 2; ++s2) {
                        vmax[s2] = NEGINF;
                        const int qrow = wbase + s2 * 16 + lc;
#pragma unroll
                        for (int kt = 0; kt < 4; ++kt)
#pragma unroll
                            for (int r = 0; r < 4; ++r) {
                                const int key = kv0 + 16 * kt + 4 * lg + r;
                                float sv = (key <= qrow) ? sacc[s2][kt][r] : NEGINF;
                                sacc[s2][kt][r] = sv;
                                vmax[s2] = fmaxf(vmax[s2], sv);
                            }
                    }
                }

                // per-strip online softmax (T13 defer-max) + P fragments + P.1 rowsum
                h16x8 pa[2][2];
#pragma unroll
                for (int s2 = 0; s2 < 2; ++s2) {
                    if (__any(vmax[s2] > mreg[s2] + DEFER_THR)) {
                        float rmax = fmaxf(vmax[s2], __shfl_xor(vmax[s2], 16, 64));
                        rmax = fmaxf(rmax, __shfl_xor(rmax, 32, 64));
                        const float mnew  = fmaxf(mreg[s2], rmax);
                        const float alpha = __builtin_amdgcn_exp2f(mreg[s2] - mnew);
                        mreg[s2] = mnew;
#pragma unroll
                        for (int r = 0; r < 4; ++r) {
                            const float ar = __shfl(alpha, 4 * lg + r, 64);
                            lacc[s2][r] *= ar;
#pragma unroll
                            for (int dt = 0; dt < 8; ++dt) o[s2][dt][r] *= ar;
                        }
                    }
#pragma unroll
                    for (int kt = 0; kt < 4; ++kt)
#pragma unroll
                        for (int r = 0; r < 4; ++r)
                            sacc[s2][kt][r] = __builtin_amdgcn_exp2f(sacc[s2][kt][r] - mreg[s2]);
#pragma unroll
                    for (int u = 0; u < 2; ++u)
                        pa[s2][u] = pack8(sacc[s2][2 * u], sacc[s2][2 * u + 1]);
                    // row-sums: lacc[r] += sum_k P[4lg+r][k]
                    lacc[s2] = __builtin_amdgcn_mfma_f32_16x16x32_f16(pa[s2][0], vones, lacc[s2], 0, 0, 0);
                    lacc[s2] = __builtin_amdgcn_mfma_f32_16x16x32_f16(pa[s2][1], vones, lacc[s2], 0, 0, 0);
                }

                // PV for both strips: linear [d][key] reads, conflict-free, pure-imm offsets
                __builtin_amdgcn_s_setprio(1);
#pragma unroll
                for (int dt = 0; dt < 8; ++dt) {
#pragma unroll
                    for (int u = 0; u < 2; ++u) {
                        union { h16x8 v8; h16x4 v4[2]; } bv;
                        bv.v4[0] = *(const h16x4*)(Vfb + dt * 16 * VPAD + 32 * u);
                        bv.v4[1] = *(const h16x4*)(Vfb + dt * 16 * VPAD + 32 * u + 16);
                        o[0][dt] = __builtin_amdgcn_mfma_f32_16x16x32_f16(pa[0][u], bv.v8, o[0][dt], 0, 0, 0);
                        o[1][dt] = __builtin_amdgcn_mfma_f32_16x16x32_f16(pa[1][u], bv.v8, o[1][dt], 0, 0, 0);
                    }
                }
                __builtin_amdgcn_s_setprio(0);
            }
            barrier_lgkm();   // single barrier per tile; global prefetch stays in flight
        } // kv tiles

        // ---- epilogue: lacc[s2][r] is the full row-sum for q = wbase+16s2+4lg+r
#pragma unroll
        for (int s2 = 0; s2 < 2; ++s2) {
#pragma unroll
            for (int r = 0; r < 4; ++r) {
                const float inv = 1.0f / lacc[s2][r];
                const int qrow  = wbase + s2 * 16 + 4 * lg + r;
                float* op = Out + (size_t)qrow * RSTRIDE + bhoff + lc;
#pragma unroll
                for (int dt = 0; dt < 8; ++dt) op[dt * 16] = o[s2][dt][r] * inv;
            }
        }
    } // half
}

extern "C" void kernel_launch(void* const* d_in, const int* in_sizes, int n_in,
                              void* d_out, int out_size, void* d_ws, size_t ws_size,
                              hipStream_t stream) {
    (void)in_sizes; (void)n_in; (void)out_size; (void)d_ws; (void)ws_size;
    const float* Q = (const float*)d_in[0];
    const float* K = (const float*)d_in[1];
    const float* V = (const float*)d_in[2];
    float* O = (float*)d_out;
    fa_fwd_kernel<<<dim3(NQT / 2, 64), 512, 0, stream>>>(Q, K, V, O);
}

// Round 15
// 104.091 us; speedup vs baseline: 1.2852x; 1.0232x over previous
//
#include <hip/hip_runtime.h>

typedef _Float16 h16;
typedef _Float16 h16x4 __attribute__((ext_vector_type(4)));
typedef _Float16 h16x8 __attribute__((ext_vector_type(8)));
typedef __fp16 fp16x2 __attribute__((ext_vector_type(2)));   // cvt_pkrtz native type
typedef float f32x4 __attribute__((ext_vector_type(4)));

#define SEQ 2048
#define RSTRIDE 8192   // b*h*d = 4*16*128
#define QTILE 256
#define NQT (SEQ / QTILE)   // 8
#define KBLK 64
#define KPAD 136       // K LDS row stride (halves): b128 r/w conflict-free in 8-lane groups
#define VPAD 76        // V LDS row stride (halves): 152B = 6 banks/row -> bijective over 16 lanes
#define DEFER_THR 8.0f

static __device__ __forceinline__ h16x8 pack8(f32x4 a, f32x4 b) {
    union { fp16x2 h2[4]; h16x8 h8; } u;
    u.h2[0] = __builtin_amdgcn_cvt_pkrtz(a[0], a[1]);
    u.h2[1] = __builtin_amdgcn_cvt_pkrtz(a[2], a[3]);
    u.h2[2] = __builtin_amdgcn_cvt_pkrtz(b[0], b[1]);
    u.h2[3] = __builtin_amdgcn_cvt_pkrtz(b[2], b[3]);
    return u.h8;
}

static __device__ __forceinline__ h16x4 pack4(float x0, float x1, float x2, float x3) {
    union { fp16x2 h2[2]; h16x4 h4; } u;
    u.h2[0] = __builtin_amdgcn_cvt_pkrtz(x0, x1);
    u.h2[1] = __builtin_amdgcn_cvt_pkrtz(x2, x3);
    return u.h4;
}

// drain ONLY LDS ops before the barrier; register-destined global loads stay in flight
static __device__ __forceinline__ void barrier_lgkm() {
    asm volatile("s_waitcnt lgkmcnt(0)" ::: "memory");
    __builtin_amdgcn_s_barrier();
}

__global__ __launch_bounds__(512, 2)
void fa_fwd_kernel(const float* __restrict__ Qg, const float* __restrict__ Kg,
                   const float* __restrict__ Vg, float* __restrict__ Out)
{
    __shared__ __attribute__((aligned(16))) h16 Kl[2][KBLK * KPAD];   // [key][d]
    __shared__ __attribute__((aligned(16))) h16 Vt[2][128 * VPAD];    // [d][key], linear

    // XCD-aware remap (256 blocks, 1/CU): XCD x owns bh in {8x..8x+7}
    const int lin = (int)blockIdx.x + 4 * (int)blockIdx.y;   // hw XCD = lin % 8
    const int bx  = (lin >> 3) & 3;               // 0..3, pairs (bx, 7-bx)
    const int bh  = 8 * (lin & 7) + (lin >> 5);   // 0..63
    const int tid  = threadIdx.x;   // 0..511 (8 waves)
    const int wave = tid >> 6;
    const int lane = tid & 63;
    const int lg   = lane >> 4;
    const int lc   = lane & 15;
    const size_t bhoff = (size_t)bh * 128;
    const float NEGINF = -__builtin_inff();
    const float SL = 0.08838834764831845f * 1.4426950408889634f;  // (1/sqrt(128))*log2(e)

    // ---- K staging geometry
    const int krow = tid >> 4;            // 0..31 (+32*it)
    const int kd0  = (tid & 15) * 8;
    const float* kbase = Kg + (size_t)krow * RSTRIDE + bhoff + kd0;
    const int kwoff = krow * KPAD + kd0;

    // ---- V staging geometry: key-group XOR-permuted so b64 LDS writes are conflict-free
    const int vkg   = ((tid >> 5) ^ ((tid & 31) >> 2)) & 15;  // key-group 0..15
    const int vkey0 = 4 * vkg;
    const int vd0   = 4 * (tid & 31);     // 0..124
    const float* vbase = Vg + (size_t)vkey0 * RSTRIDE + bhoff + vd0;

    // ---- per-lane LDS fragment bases
    const int kfoff = lc * KPAD + lg * 8;   // + kt*16*KPAD + dk*32
    const int vfoff = lc * VPAD + 4 * lg;   // + dt*16*VPAD + 32u + 16s  (all immediates)

    // ones B-fragment for the P.1 row-sum MFMA
    const h16x8 vones = h16x8{(h16)1.f,(h16)1.f,(h16)1.f,(h16)1.f,
                              (h16)1.f,(h16)1.f,(h16)1.f,(h16)1.f};

    f32x4 kra[2], krb[2], vra[4];   // prefetch registers (T14)

    for (int half = 0; half < 2; ++half) {
        const int qt = half ? (NQT - 1 - bx) : bx;
        const int q0 = qt * QTILE;
        const int wbase = q0 + wave * 32;    // wave's 32 q-rows (2 fused strips)

        // ---- Q fragments, pre-scaled
        h16x8 qf[2][4];
#pragma unroll
        for (int s2 = 0; s2 < 2; ++s2) {
            const int qrow = wbase + s2 * 16 + lc;
            const float* qp = Qg + (size_t)qrow * RSTRIDE + bhoff + lg * 8;
#pragma unroll
            for (int dk = 0; dk < 4; ++dk) {
                f32x4 a = *(const f32x4*)(qp + dk * 32);
                f32x4 b2 = *(const f32x4*)(qp + dk * 32 + 4);
#pragma unroll
                for (int j = 0; j < 4; ++j) { a[j] *= SL; b2[j] *= SL; }
                qf[s2][dk] = pack8(a, b2);
            }
        }

        f32x4 o[2][8];
#pragma unroll
        for (int s2 = 0; s2 < 2; ++s2)
#pragma unroll
            for (int dt = 0; dt < 8; ++dt) o[s2][dt] = f32x4{0.f, 0.f, 0.f, 0.f};
        float mreg[2] = {NEGINF, NEGINF};
        f32x4 lacc[2];                       // row-sums via ones-MFMA
        lacc[0] = f32x4{0.f, 0.f, 0.f, 0.f};
        lacc[1] = f32x4{0.f, 0.f, 0.f, 0.f};

        const int nkv = 4 * (qt + 1);

        // ---- prologue
#pragma unroll
        for (int it = 0; it < 2; ++it) {
            const float* gp = kbase + (size_t)(32 * it) * RSTRIDE;
            kra[it] = *(const f32x4*)gp;
            krb[it] = *(const f32x4*)(gp + 4);
        }
#pragma unroll
        for (int kk = 0; kk < 4; ++kk)
            vra[kk] = *(const f32x4*)(vbase + (size_t)kk * RSTRIDE);
        barrier_lgkm();   // previous half's LDS reads done before overwrite
        {
            h16* kw = &Kl[0][kwoff];
#pragma unroll
            for (int it = 0; it < 2; ++it)
                *(h16x8*)(kw + it * 32 * KPAD) = pack8(kra[it], krb[it]);
#pragma unroll
            for (int e = 0; e < 4; ++e)
                *(h16x4*)&Vt[0][(vd0 + e) * VPAD + vkey0] =
                    pack4(vra[0][e], vra[1][e], vra[2][e], vra[3][e]);
        }
        if (nkv > 1) {
            const size_t toff = (size_t)KBLK * RSTRIDE;
#pragma unroll
            for (int it = 0; it < 2; ++it) {
                const float* gp = kbase + toff + (size_t)(32 * it) * RSTRIDE;
                kra[it] = *(const f32x4*)gp;
                krb[it] = *(const f32x4*)(gp + 4);
            }
#pragma unroll
            for (int kk = 0; kk < 4; ++kk)
                vra[kk] = *(const f32x4*)(vbase + toff + (size_t)kk * RSTRIDE);
        }
        barrier_lgkm();   // buf0 visible; t1 loads stay in flight

        for (int t = 0; t < nkv; ++t) {
            const int kv0 = t * KBLK;
            const int cb = t & 1;
            const bool doc = (kv0 <= wbase + 31);   // wave-uniform

            h16x8 pa[2][2];

            // ---- phase 1: QK + softmax (ds_reads start at stage head, no write queue ahead)
            if (doc) {
                const h16* Kfb = &Kl[cb][kfoff];
                f32x4 sacc[2][4];
#pragma unroll
                for (int s2 = 0; s2 < 2; ++s2)
#pragma unroll
                    for (int kt = 0; kt < 4; ++kt) sacc[s2][kt] = f32x4{0.f, 0.f, 0.f, 0.f};
#pragma unroll
                for (int kt = 0; kt < 4; ++kt) {
#pragma unroll
                    for (int dk = 0; dk < 4; ++dk) {
                        h16x8 a = *(const h16x8*)(Kfb + kt * 16 * KPAD + dk * 32);
                        sacc[0][kt] = __builtin_amdgcn_mfma_f32_16x16x32_f16(a, qf[0][dk], sacc[0][kt], 0, 0, 0);
                        sacc[1][kt] = __builtin_amdgcn_mfma_f32_16x16x32_f16(a, qf[1][dk], sacc[1][kt], 0, 0, 0);
                    }
                }

                float vmax[2];
                if (kv0 + 63 <= wbase) {       // interior for both strips
#pragma unroll
                    for (int s2 = 0; s2 < 2; ++s2) {
                        const float a0 = fmaxf(fmaxf(sacc[s2][0][0], sacc[s2][0][1]), sacc[s2][0][2]);
                        const float a1 = fmaxf(fmaxf(sacc[s2][0][3], sacc[s2][1][0]), sacc[s2][1][1]);
                        const float a2 = fmaxf(fmaxf(sacc[s2][1][2], sacc[s2][1][3]), sacc[s2][2][0]);
                        const float a3 = fmaxf(fmaxf(sacc[s2][2][1], sacc[s2][2][2]), sacc[s2][2][3]);
                        const float a4 = fmaxf(fmaxf(sacc[s2][3][0], sacc[s2][3][1]), sacc[s2][3][2]);
                        const float b0 = fmaxf(fmaxf(a0, a1), a2);
                        const float b1 = fmaxf(fmaxf(a3, a4), sacc[s2][3][3]);
                        vmax[s2] = fmaxf(b0, b1);
                    }
                } else {
#pragma unroll
                    for (int s2 = 0; s2 < 2; ++s2) {
                        vmax[s2] = NEGINF;
                        const int qrow = wbase + s2 * 16 + lc;
#pragma unroll
                        for (int kt = 0; kt < 4; ++kt)
#pragma unroll
                            for (int r = 0; r < 4; ++r) {
                                const int key = kv0 + 16 * kt + 4 * lg + r;
                                float sv = (key <= qrow) ? sacc[s2][kt][r] : NEGINF;
                                sacc[s2][kt][r] = sv;
                                vmax[s2] = fmaxf(vmax[s2], sv);
                            }
                    }
                }

#pragma unroll
                for (int s2 = 0; s2 < 2; ++s2) {
                    if (__any(vmax[s2] > mreg[s2] + DEFER_THR)) {
                        float rmax = fmaxf(vmax[s2], __shfl_xor(vmax[s2], 16, 64));
                        rmax = fmaxf(rmax, __shfl_xor(rmax, 32, 64));
                        const float mnew  = fmaxf(mreg[s2], rmax);
                        const float alpha = __builtin_amdgcn_exp2f(mreg[s2] - mnew);
                        mreg[s2] = mnew;
#pragma unroll
                        for (int r = 0; r < 4; ++r) {
                            const float ar = __shfl(alpha, 4 * lg + r, 64);
                            lacc[s2][r] *= ar;
#pragma unroll
                            for (int dt = 0; dt < 8; ++dt) o[s2][dt][r] *= ar;
                        }
                    }
#pragma unroll
                    for (int kt = 0; kt < 4; ++kt)
#pragma unroll
                        for (int r = 0; r < 4; ++r)
                            sacc[s2][kt][r] = __builtin_amdgcn_exp2f(sacc[s2][kt][r] - mreg[s2]);
#pragma unroll
                    for (int u = 0; u < 2; ++u)
                        pa[s2][u] = pack8(sacc[s2][2 * u], sacc[s2][2 * u + 1]);
                    lacc[s2] = __builtin_amdgcn_mfma_f32_16x16x32_f16(pa[s2][0], vones, lacc[s2], 0, 0, 0);
                    lacc[s2] = __builtin_amdgcn_mfma_f32_16x16x32_f16(pa[s2][1], vones, lacc[s2], 0, 0, 0);
                }
            }

            // ---- phase 2: staging writes t+1 (hide under PV's MFMA cluster below)
            if (t + 1 < nkv) {
                h16* kw = &Kl[cb ^ 1][kwoff];
#pragma unroll
                for (int it = 0; it < 2; ++it)
                    *(h16x8*)(kw + it * 32 * KPAD) = pack8(kra[it], krb[it]);
#pragma unroll
                for (int e = 0; e < 4; ++e)
                    *(h16x4*)&Vt[cb ^ 1][(vd0 + e) * VPAD + vkey0] =
                        pack4(vra[0][e], vra[1][e], vra[2][e], vra[3][e]);
            }
            // ---- phase 3: issue t+2 global loads (L2 latency covered by PV)
            if (t + 2 < nkv) {
                const size_t toff = (size_t)(kv0 + 2 * KBLK) * RSTRIDE;
#pragma unroll
                for (int it = 0; it < 2; ++it) {
                    const float* gp = kbase + toff + (size_t)(32 * it) * RSTRIDE;
                    kra[it] = *(const f32x4*)gp;
                    krb[it] = *(const f32x4*)(gp + 4);
                }
#pragma unroll
                for (int kk = 0; kk < 4; ++kk)
                    vra[kk] = *(const f32x4*)(vbase + toff + (size_t)kk * RSTRIDE);
            }

            // ---- phase 4: PV (linear [d][key] reads, conflict-free, pure-imm offsets)
            if (doc) {
                const h16* Vfb = &Vt[cb][vfoff];
#pragma unroll
                for (int dt = 0; dt < 8; ++dt) {
#pragma unroll
                    for (int u = 0; u < 2; ++u) {
                        union { h16x8 v8; h16x4 v4[2]; } bv;
                        bv.v4[0] = *(const h16x4*)(Vfb + dt * 16 * VPAD + 32 * u);
                        bv.v4[1] = *(const h16x4*)(Vfb + dt * 16 * VPAD + 32 * u + 16);
                        o[0][dt] = __builtin_amdgcn_mfma_f32_16x16x32_f16(pa[0][u], bv.v8, o[0][dt], 0, 0, 0);
                        o[1][dt] = __builtin_amdgcn_mfma_f32_16x16x32_f16(pa[1][u], bv.v8, o[1][dt], 0, 0, 0);
                    }
                }
            }
            barrier_lgkm();   // single barrier per tile; global prefetch stays in flight
        } // kv tiles

        // ---- epilogue: lacc[s2][r] is the full row-sum for q = wbase+16s2+4lg+r
#pragma unroll
        for (int s2 = 0; s2 < 2; ++s2) {
#pragma unroll
            for (int r = 0; r < 4; ++r) {
                const float inv = 1.0f / lacc[s2][r];
                const int qrow  = wbase + s2 * 16 + 4 * lg + r;
                float* op = Out + (size_t)qrow * RSTRIDE + bhoff + lc;
#pragma unroll
                for (int dt = 0; dt < 8; ++dt) op[dt * 16] = o[s2][dt][r] * inv;
            }
        }
    } // half
}

extern "C" void kernel_launch(void* const* d_in, const int* in_sizes, int n_in,
                              void* d_out, int out_size, void* d_ws, size_t ws_size,
                              hipStream_t stream) {
    (void)in_sizes; (void)n_in; (void)out_size; (void)d_ws; (void)ws_size;
    const float* Q = (const float*)d_in[0];
    const float* K = (const float*)d_in[1];
    const float* V = (const float*)d_in[2];
    float* O = (float*)d_out;
    fa_fwd_kernel<<<dim3(NQT / 2, 64), 512, 0, stream>>>(Q, K, V, O);
}